// Round 11
// baseline (902.425 us; speedup 1.0000x reference)
//
#include <hip/hip_runtime.h>
#include <hip/hip_bf16.h>
#include <math.h>

// Shapes (fixed by the reference)
#define Bn 16
#define Sn 64
#define Tn 64
#define En 256
#define Hn 512
#define VS 32000
#define Jn 201
#define Mn 100

// Workspace layout (float offsets)
#define O_HCATF  0                      // hcat bf16 A-frags [64 mt][32 ks][64 lane][8] = 524288 fl
#define O_DENOM  524288                 // [1024]
#define O_NULLD  525312                 // [64]
#define O_SLOTS  525376                 // 32 slots x 64 uints (256B apart)
#define O_HBUF   527424                 // u32 [2 pp][2 dir][16 b][256] = 32768 fl
#define ZERO_N   560192
#define O_NS     560192                 // [512]
#define O_TS     560704                 // [1024][512] fp32; pre-LSTM holds W_comb fp32, proj overwrites with ts
#define O_WCOMB  560704                 // alias: W_comb = Wproj_t @ nnW fp32 [1024][512]
#define O_TSF    1084992                // ts A-frags bf16 -> 262144 fl -> 1347136
#define O_WCOMBF 1347136                // W_comb B-frags -> 262144 fl -> 1609280
#define O_WPTAF  1609280                // Wproj_t A-frags -> 131072 -> 1740352
#define O_TT     1740352                // [1024][512] fp32 -> 2264640
#define O_XF     2264640                // emb-gather A-frags -> 131072 -> 2395712 (dead after gx launch)
#define O_WVC    2264640                // gathered Wv columns [1024][512] fp32 (filler-written during LSTM)
#define O_WXFW   2395712                // Wx_fw B-frags -> 262144 -> 2657856 (dead after gx launch)
#define O_WXBW   2657856                // Wx_bw B-frags -> 262144 -> 2920000 (dead after gx launch)
#define O_WPEF   2920000                // Wproj_e B-frags -> 262144 -> 3182144 (filler-written during LSTM)
#define O_NNWF   3313216                // nnW B-frags -> 65536 -> 3378752 (mega_prep-written, read by gxw)
#define O_GX     3378752                // [2][1024][2048] fp32 -> 7573056 (LSTM-live)

typedef __attribute__((ext_vector_type(8))) short short8;
typedef __attribute__((ext_vector_type(4))) float f32x4;

__device__ __forceinline__ float sigf(float x) { return 1.0f / (1.0f + expf(-x)); }
__device__ __forceinline__ unsigned short tobf(float x) {
    __hip_bfloat16 h = __float2bfloat16(x);
    return *reinterpret_cast<unsigned short*>(&h);
}

// ---------------- device conversion bodies ----------------
__device__ __forceinline__ void dconvA(const float* __restrict__ A, uint4* __restrict__ out,
                                       int K, const int* __restrict__ gidx, int g) {
    int Kd = K >> 5;
    int lane = g & 63, t = g >> 6;
    int ks = t % Kd, mt = t / Kd;
    int m = mt * 16 + (lane & 15);
    int k0 = ks * 32 + (lane >> 4) * 8;
    const float* p = (gidx ? A + (size_t)gidx[m] * K : A + (size_t)m * K) + k0;
    float4 f0 = *(const float4*)(p);
    float4 f1 = *(const float4*)(p + 4);
    unsigned short u[8] = {tobf(f0.x), tobf(f0.y), tobf(f0.z), tobf(f0.w),
                           tobf(f1.x), tobf(f1.y), tobf(f1.z), tobf(f1.w)};
    out[g] = *(uint4*)u;
}

__device__ __forceinline__ void dconvB(const float* __restrict__ B, uint4* __restrict__ out,
                                       int N, int K, int g) {
    int Kd = K >> 5;
    int lane = g & 63, t = g >> 6;
    int ks = t % Kd, nt = t / Kd;
    int n = nt * 16 + (lane & 15);
    int k0 = ks * 32 + (lane >> 4) * 8;
    const float* p = B + (size_t)k0 * N + n;
    unsigned short u[8];
#pragma unroll
    for (int j = 0; j < 8; j++) u[j] = tobf(p[(size_t)j * N]);
    out[g] = *(uint4*)u;
}

// ---------------- fused prolog: zero + all pre-LSTM converts ----------------
__global__ __launch_bounds__(256) void mega_prep_k(float4* __restrict__ zdst, int zn4,
                                                   const float* __restrict__ emb,
                                                   const int* __restrict__ targets,
                                                   uint4* __restrict__ xf,
                                                   const float* __restrict__ wxfw, uint4* __restrict__ wxfwf,
                                                   const float* __restrict__ wxbw, uint4* __restrict__ wxbwf,
                                                   const float* __restrict__ wpt, uint4* __restrict__ wptaf,
                                                   const float* __restrict__ nnw, uint4* __restrict__ nnwf) {
    int blk = blockIdx.x, tid = threadIdx.x;
    if (blk < 548) {
        int i = blk * 256 + tid;
        if (i < zn4) zdst[i] = make_float4(0.f, 0.f, 0.f, 0.f);
    } else if (blk < 676) {
        dconvA(emb, xf, 256, targets, (blk - 548) * 256 + tid);
    } else if (blk < 932) {
        dconvB(wxfw, wxfwf, 2048, 256, (blk - 676) * 256 + tid);
    } else if (blk < 1188) {
        dconvB(wxbw, wxbwf, 2048, 256, (blk - 932) * 256 + tid);
    } else if (blk < 1316) {
        dconvA(wpt, wptaf, 256, nullptr, (blk - 1188) * 256 + tid);   // Wproj_t A-frags [1024][256]
    } else {
        dconvB(nnw, nnwf, 512, 256, (blk - 1316) * 256 + tid);        // nnW B-frags [256][512]
    }
}

// ---------------- generic MFMA GEMM body: C = act(A@B + bias), fp32 out ----------------
template <int ACT>
__device__ __forceinline__ void gemm_body(const uint4* __restrict__ af,
                                          const uint4* __restrict__ bf,
                                          const float* __restrict__ bias,
                                          float* __restrict__ C, int N, int Kd,
                                          int bx, int by) {
    int tid = threadIdx.x, w = tid >> 6, lane = tid & 63;
    int ntb = bx * 8 + w * 2;
    int mtb = by * 8;
    f32x4 acc[8][2];
#pragma unroll
    for (int i = 0; i < 8; i++)
#pragma unroll
        for (int j = 0; j < 2; j++) acc[i][j] = 0.0f;
    for (int ks = 0; ks < Kd; ++ks) {
        uint4 b0 = bf[(size_t)(ntb * Kd + ks) * 64 + lane];
        uint4 b1 = bf[(size_t)((ntb + 1) * Kd + ks) * 64 + lane];
#pragma unroll
        for (int i = 0; i < 8; i++) {
            uint4 a = af[(size_t)((mtb + i) * Kd + ks) * 64 + lane];
            acc[i][0] = __builtin_amdgcn_mfma_f32_16x16x32_bf16(
                *reinterpret_cast<short8*>(&a), *reinterpret_cast<short8*>(&b0), acc[i][0], 0, 0, 0);
            acc[i][1] = __builtin_amdgcn_mfma_f32_16x16x32_bf16(
                *reinterpret_cast<short8*>(&a), *reinterpret_cast<short8*>(&b1), acc[i][1], 0, 0, 0);
        }
    }
    int n0 = ntb * 16 + (lane & 15);
    int q = lane >> 4;
    float bs0 = bias ? bias[n0] : 0.f;
    float bs1 = bias ? bias[n0 + 16] : 0.f;
#pragma unroll
    for (int i = 0; i < 8; i++)
#pragma unroll
        for (int r = 0; r < 4; r++) {
            int m = (mtb + i) * 16 + q * 4 + r;
            float v0 = acc[i][0][r] + bs0;
            float v1 = acc[i][1][r] + bs1;
            if (ACT == 1) { v0 = tanhf(v0); v1 = tanhf(v1); }
            C[(size_t)m * N + n0] = v0;
            C[(size_t)m * N + n0 + 16] = v1;
        }
}

// merged: both gx GEMMs + W_comb GEMM
__global__ __launch_bounds__(256) void gxw_gemm_k(const uint4* __restrict__ xf,
                                                  const uint4* __restrict__ wxfwf,
                                                  const uint4* __restrict__ wxbwf,
                                                  const float* __restrict__ b_fw,
                                                  const float* __restrict__ b_bw,
                                                  float* __restrict__ gx,
                                                  const uint4* __restrict__ wptaf,
                                                  const uint4* __restrict__ nnwf,
                                                  float* __restrict__ wcomb) {
    int bx = blockIdx.x;
    if (bx < 16)      gemm_body<0>(xf, wxfwf, b_fw, gx, 2048, 8, bx, blockIdx.y);
    else if (bx < 32) gemm_body<0>(xf, wxbwf, b_bw, gx + 2097152, 2048, 8, bx - 16, blockIdx.y);
    else              gemm_body<0>(wptaf, nnwf, nullptr, wcomb, 512, 8, bx - 32, blockIdx.y);
}

// merged: ts = hcat@Wproj_e (plain) and tt = tanh(hcat@W_comb + nnb)
__global__ __launch_bounds__(256) void projts_k(const uint4* __restrict__ hcatf,
                                                const uint4* __restrict__ wpef,
                                                const uint4* __restrict__ wcombf,
                                                const float* __restrict__ nnb,
                                                float* __restrict__ ts,
                                                float* __restrict__ tt) {
    int bx = blockIdx.x;
    if (bx < 4) gemm_body<0>(hcatf, wpef, nullptr, ts, 512, 32, bx, blockIdx.y);
    else        gemm_body<1>(hcatf, wcombf, nnb, tt, 512, 32, bx - 4, blockIdx.y);
}

// ---------------- fused persistent LSTM + fillers + clock-hold spinners ----------------
// blocks    0..31 : r1's proven barrier-protocol LSTM (verbatim).
// blocks   32..156: null state + null denominator.
// blocks  157..284: gather emission's Wv columns into O_WVC.
// blocks  285..540: Wproj_e -> B-frags (O_WPEF).
// blocks  541..796: W_comb -> B-frags (O_WCOMBF).
// blocks 797..1020: SPINNERS — dependent-FMA chains on the otherwise-idle CUs to hold
//   SCLK up (theory: the 446 us LSTM is 3.5x slower than its latency model because the
//   power governor downclocks a ~2%-occupancy GPU). Self-terminating: poll LSTM block 0's
//   progress flag and exit at step 63. No memory writes, no clock-rate assumptions,
//   cannot deadlock (flag advances unconditionally every LSTM step).
__global__ __launch_bounds__(256, 1) void lstm_fused_k(const float* __restrict__ wh_fw,
                                                       const float* __restrict__ wh_bw,
                                                       const float* __restrict__ gx,
                                                       const int* __restrict__ lengths,
                                                       unsigned* __restrict__ hbuf32,
                                                       unsigned* __restrict__ hcat32,
                                                       unsigned* __restrict__ slots,
                                                       const float* __restrict__ Wv,
                                                       const float* __restrict__ emb,
                                                       const int* __restrict__ tnull,
                                                       const float* __restrict__ nnW,
                                                       const float* __restrict__ nnb,
                                                       const float* __restrict__ bv,
                                                       float* __restrict__ ns,
                                                       float* __restrict__ nd,
                                                       const int* __restrict__ sources,
                                                       float* __restrict__ wvc,
                                                       const float* __restrict__ wpe, uint4* __restrict__ wpef,
                                                       const float* __restrict__ wcomb, uint4* __restrict__ wcombf) {
    int blk = blockIdx.x;
    int tid = threadIdx.x;

    if (blk >= 797) {
        // ---- clock-hold spinner: dependent FMA chain until LSTM nearly done ----
        float x = 1.0f + (float)tid;
        while (__hip_atomic_load(&slots[0], __ATOMIC_RELAXED, __HIP_MEMORY_SCOPE_AGENT) < 63u) {
#pragma unroll 8
            for (int i = 0; i < 2048; i++) x = fmaf(x, 1.000001f, 1e-7f);
        }
        if (x == 0.0f) ns[0] = x;   // unreachable (x >= 1 and grows); keeps the chain live
        return;
    }
    if (blk >= 541) {                 // W_comb -> B-frags (N=512, K=1024)
        dconvB(wcomb, wcombf, 512, 1024, (blk - 541) * 256 + tid);
        return;
    }
    if (blk >= 285) {                 // Wproj_e B-frags
        dconvB(wpe, wpef, 512, 1024, (blk - 285) * 256 + tid);
        return;
    }
    if (blk >= 157) {
        // ---- gather emission's Wv columns: wvc[ci][k] = Wv[k][sources[ci]] ----
        int cb = blk - 157;           // 0..127, 8 columns each
#pragma unroll
        for (int cc = 0; cc < 8; ++cc) {
            int ci = cb * 8 + cc;
            int c = sources[ci];
            float v0 = Wv[(size_t)tid * VS + c];
            float v1 = Wv[(size_t)(tid + 256) * VS + c];
            wvc[(size_t)ci * 512 + tid] = v0;
            wvc[(size_t)ci * 512 + 256 + tid] = v1;
        }
        return;
    }
    if (blk >= 32) {
        // ---- null state + denom ----
        __shared__ float xn[En];
        __shared__ float nsl[Hn];
        __shared__ float red[4];
        int bid = blk - 32;
        xn[tid] = emb[(size_t)tnull[0] * En + tid];
        __syncthreads();
#pragma unroll
        for (int hh = 0; hh < 2; hh++) {
            int h = tid + hh * 256;
            float a = nnb[h];
            for (int e = 0; e < En; e++) a += xn[e] * nnW[(size_t)e * Hn + h];
            float v = tanhf(a);
            nsl[h] = v;
            if (bid == 0) ns[h] = v;
        }
        __syncthreads();
        int v = bid * 256 + tid;
        float a = bv[v];
        for (int k = 0; k < Hn; k++) a += nsl[k] * Wv[(size_t)k * VS + v];
        float e = expf(a);
        for (int o = 1; o < 64; o <<= 1) e += __shfl_xor(e, o);
        if ((tid & 63) == 0) red[tid >> 6] = e;
        __syncthreads();
        if (tid == 0) atomicAdd(nd, red[0] + red[1] + red[2] + red[3]);
        return;
    }

    // ---- r1 persistent bidirectional LSTM (verbatim) ----
    __shared__ uint4 whf[8192];       // 128 KB B-frags
    __shared__ float raw[32][129];
    __shared__ int lenS[16];
    int dir = blk >> 4;
    int u0 = (blk & 15) * 32;
    const float* wh = dir ? wh_bw : wh_fw;
    if (tid < 16) lenS[tid] = lengths[tid];

    // one-time Wh -> bf16 B-frag staging
    for (int chunk = 0; chunk < 16; ++chunk) {
#pragma unroll
        for (int it = 0; it < 16; ++it) {
            int li = it * 256 + tid;
            int kl = li >> 7, c = li & 127;
            int g = c >> 5, ub = c & 31;
            raw[kl][c] = wh[(size_t)(chunk * 32 + kl) * 2048 + g * 512 + u0 + ub];
        }
        __syncthreads();
#pragma unroll
        for (int it = 0; it < 2; ++it) {
            int idx = tid * 2 + it;
            int w = idx >> 7, t = (idx >> 6) & 1, lane = idx & 63;
            int n = lane & 15, uu = n >> 1, p = n & 1;
            int cc = (t * 2 + p) * 32 + w * 8 + uu;
            int kb = (lane >> 4) * 8;
            unsigned short u8[8];
#pragma unroll
            for (int j = 0; j < 8; j++) u8[j] = tobf(raw[kb + j][cc]);
            whf[((w * 2 + t) * 16 + chunk) * 64 + lane] = *(uint4*)u8;
        }
        __syncthreads();
    }

    int wv = tid >> 6, lane = tid & 63;
    int n = lane & 15, uu = n >> 1, q = lane >> 4;
    int u = u0 + wv * 8 + uu;
    float creg[4] = {0.f, 0.f, 0.f, 0.f};
    unsigned short hbf[4] = {0, 0, 0, 0};

    for (int s = 0; s < 64; ++s) {
        // ---- gx prefetch (normal cached loads, issued first) ----
        float gxi[4], gxj[4], gxf[4], gxo[4];
#pragma unroll
        for (int r = 0; r < 4; r++) {
            int b = q * 4 + r;
            int len = lenS[b];
            int tc = dir ? (len - 1 - s) : s;
            tc = tc < 0 ? 0 : tc;
            const float* gp = gx + (size_t)dir * 2097152 + (size_t)(b * 64 + tc) * 2048 + u;
            gxi[r] = gp[0]; gxj[r] = gp[512]; gxf[r] = gp[1024]; gxo[r] = gp[1536];
        }
        // ---- A-frags: bypass-atomic u64 loads of h (b = n, k = units) ----
        const unsigned long long* hb64 =
            (const unsigned long long*)(hbuf32 + (((s & 1) * 2 + dir) * 16) * 256);
        unsigned long long h64[32];
#pragma unroll
        for (int ks = 0; ks < 16; ks++) {
            int idx = n * 128 + ks * 8 + q * 2;
            h64[2 * ks] = __hip_atomic_load(hb64 + idx, __ATOMIC_RELAXED, __HIP_MEMORY_SCOPE_AGENT);
            h64[2 * ks + 1] = __hip_atomic_load(hb64 + idx + 1, __ATOMIC_RELAXED, __HIP_MEMORY_SCOPE_AGENT);
        }
        // ---- MFMA ----
        f32x4 acc0 = {0.f, 0.f, 0.f, 0.f}, acc1 = {0.f, 0.f, 0.f, 0.f};
#pragma unroll
        for (int ks = 0; ks < 16; ks++) {
            unsigned long long av[2] = {h64[2 * ks], h64[2 * ks + 1]};
            short8 a = *reinterpret_cast<short8*>(av);
            uint4 b0 = whf[((wv * 2 + 0) * 16 + ks) * 64 + lane];
            uint4 b1 = whf[((wv * 2 + 1) * 16 + ks) * 64 + lane];
            acc0 = __builtin_amdgcn_mfma_f32_16x16x32_bf16(a, *reinterpret_cast<short8*>(&b0), acc0, 0, 0, 0);
            acc1 = __builtin_amdgcn_mfma_f32_16x16x32_bf16(a, *reinterpret_cast<short8*>(&b1), acc1, 0, 0, 0);
        }
        // ---- gates (even lanes i/f in acc0/acc1; odd lanes j/o of same unit) ----
#pragma unroll
        for (int r = 0; r < 4; r++) {
            float jvv = __shfl_xor(acc0[r], 1);
            float ovv = __shfl_xor(acc1[r], 1);
            int b = q * 4 + r;
            int len = lenS[b];
            float gi = acc0[r] + gxi[r];
            float gj = jvv + gxj[r];
            float gf = acc1[r] + gxf[r];
            float go = ovv + gxo[r];
            float cn = sigf(gf + 1.0f) * creg[r] + sigf(gi) * tanhf(gj);
            float hn = sigf(go) * tanhf(cn);
            if (s < len) { creg[r] = cn; hbf[r] = tobf(hn); }
        }
        // ---- pack unit pairs and store (lanes n%4==0 own units u,u+1) ----
#pragma unroll
        for (int r = 0; r < 4; r++) {
            unsigned self = hbf[r];
            unsigned part = (unsigned)__shfl_xor((int)self, 2) & 0xffffu;
            if ((n & 3) == 0) {
                unsigned pk = self | (part << 16);
                int b = q * 4 + r;
                __hip_atomic_store(
                    hbuf32 + ((((s + 1) & 1) * 2 + dir) * 16 + b) * 256 + (u >> 1), pk,
                    __ATOMIC_RELAXED, __HIP_MEMORY_SCOPE_AGENT);
                int len = lenS[b];
                if (s < len) {
                    int tin = dir ? (len - 1 - s) : s;
                    int row = b * 64 + tin, col = dir * 512 + u;
                    int mt = row >> 4, ksx = col >> 5;
                    int lanep = (row & 15) | (((col >> 3) & 3) << 4);
                    hcat32[(size_t)(((mt * 32 + ksx) * 64 + lanep) * 4) + ((col & 7) >> 1)] = pk;
                }
            }
        }
        if (s == 63) break;
        __syncthreads();  // vmcnt(0) drain: h stores at coherence point before flag
        if (tid == 0)     // RELAXED flag: no per-step buffer_wbl2
            __hip_atomic_store(&slots[blk * 64], (unsigned)(s + 1), __ATOMIC_RELAXED,
                               __HIP_MEMORY_SCOPE_AGENT);
        if (tid < 16) {
            while (__hip_atomic_load(&slots[(dir * 16 + tid) * 64], __ATOMIC_RELAXED,
                                     __HIP_MEMORY_SCOPE_AGENT) < (unsigned)(s + 1)) {
                __builtin_amdgcn_s_sleep(1);
            }
        }
        __syncthreads();
    }
}

// ---------------- convA (ts->tsf, blocks 0..255) + transition (blocks 256..1279) ----------------
// Both small-LDS (~5 KB) and both depend only on projts -> run concurrently at full
// occupancy. (r9 lesson: do NOT co-kernel transition with the 128 KB-LDS phaseA.)
__global__ __launch_bounds__(256) void convtr_k(const float* __restrict__ ts,
                                                uint4* __restrict__ tsf,
                                                const float* __restrict__ tt,
                                                const float* __restrict__ Wj,
                                                const float* __restrict__ bj,
                                                const float* __restrict__ Wp0,
                                                const float* __restrict__ bp0,
                                                float* __restrict__ trans,
                                                float* __restrict__ tlog) {
    __shared__ float ttl[512];
    __shared__ float jrow[Jn], ljrow[Jn];
    __shared__ float sred[256];
    __shared__ float p0_s, lp0_s;
    int blk = blockIdx.x;
    int tid = threadIdx.x;
    if (blk < 256) {
        dconvA(ts, tsf, 512, nullptr, blk * 256 + tid);
        return;
    }
    // ---- transition (r6 body, 256 threads, full occupancy) ----
    int tb = blk - 256;
    int b = tb >> 6, i = tb & 63;
    {
        const float* trr = tt + (size_t)tb * 512;
        if (tid < 128) *(float4*)&ttl[tid * 4] = *(const float4*)(trr + tid * 4);
    }
    __syncthreads();
    bool isj = tid < Jn;
    bool isp = tid == Jn;
    float l = 0.f;
    if (isj || isp) {
        const float* wb = isj ? (Wj + tid) : Wp0;
        int stride = isj ? Jn : 1;
        float a = isj ? bj[tid] : bp0[0];
        for (int k = 0; k < 512; k++) a += ttl[k] * wb[(size_t)k * stride];
        l = a;
    }
    sred[tid] = isj ? l : -1e30f;
    __syncthreads();
    for (int o = 128; o > 0; o >>= 1) {
        if (tid < o) sred[tid] = fmaxf(sred[tid], sred[tid + o]);
        __syncthreads();
    }
    float m = sred[0];
    __syncthreads();
    float ex = isj ? expf(l - m) : 0.f;
    sred[tid] = ex;
    __syncthreads();
    for (int o = 128; o > 0; o >>= 1) {
        if (tid < o) sred[tid] += sred[tid + o];
        __syncthreads();
    }
    float S = sred[0];
    if (isj) {
        jrow[tid] = ex / S;
        ljrow[tid] = (l - m) - logf(S);
    }
    if (isp) {
        float pv = 1.f / (1.f + expf(-l));
        p0_s = pv;
        lp0_s = logf(pv);
    }
    __syncthreads();
    if (tid < 128) {
        int j = tid;
        float tv, lv;
        if (j < 64) {
            int id = Mn + j - i;
            tv = jrow[id];
            lv = ljrow[id];
        } else {
            bool dg = (j - 64) == i;
            tv = dg ? p0_s : 0.f;
            lv = dg ? lp0_s : 0.f;
        }
        size_t r1 = (size_t)(b * 128 + i) * 128 + j;
        size_t r2 = (size_t)(b * 128 + 64 + i) * 128 + j;
        trans[r1] = tv;
        trans[r2] = tv;
        tlog[r1] = lv;
        tlog[r2] = lv;
    }
}

// ---------------- Phase A: MFMA bf16 row-sum-of-exp, Wv converted in-LDS (standalone) ----------------
__global__ __launch_bounds__(256) void phaseA_mfma_k(const uint4* __restrict__ tsb,
                                                     const float* __restrict__ Wv,
                                                     const float* __restrict__ bv,
                                                     float* __restrict__ denom) {
    __shared__ uint4 wls[8192];      // 128 KB: [8 tiles][16 ks][64 lane]
    __shared__ float redL[4][128];
    int tid = threadIdx.x;
    int wave = tid >> 6, lane = tid & 63;
    for (int it = 0; it < 32; ++it) {
        int g = it * 256 + tid;
        int gl = g & 63, t = g >> 6;
        int ks = t & 15, tl = t >> 4;
        int nt = blockIdx.x * 8 + tl;
        int nn = nt * 16 + (gl & 15);
        int k0 = ks * 32 + (gl >> 4) * 8;
        const float* p = Wv + (size_t)k0 * VS + nn;
        unsigned short u[8];
#pragma unroll
        for (int j = 0; j < 8; j++) u[j] = tobf(p[(size_t)j * VS]);
        wls[g] = *(uint4*)u;
    }
    __syncthreads();

    int ntbase = blockIdx.x * 8 + wave * 2;
    float bv0 = bv[ntbase * 16 + (lane & 15)];
    float bv1 = bv[(ntbase + 1) * 16 + (lane & 15)];
    int q = lane >> 4;
    for (int mc = 0; mc < 8; ++mc) {
        f32x4 acc[8][2];
#pragma unroll
        for (int i = 0; i < 8; i++)
#pragma unroll
            for (int j = 0; j < 2; j++) acc[i][j] = 0.0f;
#pragma unroll 4
        for (int ks = 0; ks < 16; ++ks) {
            short8 a[8], b[2];
#pragma unroll
            for (int i = 0; i < 8; i++) {
                int mt = mc * 8 + i;
                uint4 t = tsb[(size_t)(mt * 16 + ks) * 64 + lane];
                a[i] = *reinterpret_cast<short8*>(&t);
            }
#pragma unroll
            for (int j = 0; j < 2; j++) {
                uint4 t = wls[((wave * 2 + j) * 16 + ks) * 64 + lane];
                b[j] = *reinterpret_cast<short8*>(&t);
            }
#pragma unroll
            for (int i = 0; i < 8; i++)
#pragma unroll
                for (int j = 0; j < 2; j++)
                    acc[i][j] = __builtin_amdgcn_mfma_f32_16x16x32_bf16(a[i], b[j], acc[i][j], 0, 0, 0);
        }
#pragma unroll
        for (int i = 0; i < 8; i++) {
#pragma unroll
            for (int r = 0; r < 4; r++) {
                float e = __expf(acc[i][0][r] + bv0) + __expf(acc[i][1][r] + bv1);
                e += __shfl_xor(e, 1);
                e += __shfl_xor(e, 2);
                e += __shfl_xor(e, 4);
                e += __shfl_xor(e, 8);
                if ((lane & 15) == 0) redL[wave][i * 16 + q * 4 + r] = e;
            }
        }
        __syncthreads();
        if (tid < 128) {
            float v = redL[0][tid] + redL[1][tid] + redL[2][tid] + redL[3][tid];
            atomicAdd(&denom[mc * 128 + tid], v);
        }
        __syncthreads();
    }
}

// ---------------- emission assembly (reads pre-gathered Wv columns) ----------------
__global__ __launch_bounds__(512) void emission_k(const float* __restrict__ ts,
                                                  const float* __restrict__ wvc,
                                                  const float* __restrict__ bv,
                                                  const int* __restrict__ sources,
                                                  const float* __restrict__ ns,
                                                  const float* __restrict__ denom,
                                                  const float* __restrict__ nulld,
                                                  float* __restrict__ em) {
    __shared__ float colv[512];
    __shared__ float red[64][9];
    __shared__ float red2[8];
    __shared__ float env_s, bvc_s;
    int b = blockIdx.y, sc = blockIdx.x;
    int tid = threadIdx.x;
    for (int qq = 0; qq < 8; ++qq) {
        int s = sc * 8 + qq;
        int ci = b * 64 + s;
        __syncthreads();
        colv[tid] = wvc[(size_t)ci * 512 + tid];
        if (tid == 0) bvc_s = bv[sources[ci]];
        __syncthreads();
        int r = tid & 63, ksl = tid >> 6;
        const float* tr = ts + (size_t)(b * 64 + r) * 512 + ksl * 64;
        float p = 0.f;
#pragma unroll
        for (int k4 = 0; k4 < 16; k4++) {
            float4 t4 = *(const float4*)(tr + k4 * 4);
            float4 c4 = *(const float4*)&colv[ksl * 64 + k4 * 4];
            p += t4.x * c4.x + t4.y * c4.y + t4.z * c4.z + t4.w * c4.w;
        }
        red[r][ksl] = p;
        if (tid < 8) {
            float pn = 0.f;
#pragma unroll
            for (int k4 = 0; k4 < 16; k4++) {
                float4 n4 = *(const float4*)(ns + tid * 64 + k4 * 4);
                float4 c4 = *(const float4*)&colv[tid * 64 + k4 * 4];
                pn += n4.x * c4.x + n4.y * c4.y + n4.z * c4.z + n4.w * c4.w;
            }
            red2[tid] = pn;
        }
        __syncthreads();
        if (tid < 64) {
            float dot = red[tid][0] + red[tid][1] + red[tid][2] + red[tid][3] +
                        red[tid][4] + red[tid][5] + red[tid][6] + red[tid][7];
            float ew = expf(dot + bvc_s) / denom[b * 64 + tid];
            em[(size_t)(b * 128 + tid) * 64 + s] = ew;
        } else if (tid == 64) {
            float dn = red2[0] + red2[1] + red2[2] + red2[3] +
                       red2[4] + red2[5] + red2[6] + red2[7];
            env_s = expf(dn + bvc_s) / nulld[0];
        }
        __syncthreads();
        if (tid < 64) em[(size_t)(b * 128 + 64 + tid) * 64 + s] = env_s;
    }
}

extern "C" void kernel_launch(void* const* d_in, const int* in_sizes, int n_in,
                              void* d_out, int out_size, void* d_ws, size_t ws_size,
                              hipStream_t stream) {
    const int* sources = (const int*)d_in[0];
    const int* targets = (const int*)d_in[1];
    const int* tnull = (const int*)d_in[2];
    const int* lengths = (const int*)d_in[3];
    const float* emb = (const float*)d_in[4];
    const float* nnW = (const float*)d_in[5];
    const float* nnb = (const float*)d_in[6];
    const float* Wx_fw = (const float*)d_in[7];
    const float* Wh_fw = (const float*)d_in[8];
    const float* b_fw = (const float*)d_in[9];
    const float* Wx_bw = (const float*)d_in[10];
    const float* Wh_bw = (const float*)d_in[11];
    const float* b_bw = (const float*)d_in[12];
    const float* Wproj_e = (const float*)d_in[13];
    const float* Wv = (const float*)d_in[14];
    const float* bv = (const float*)d_in[15];
    const float* Wproj_t = (const float*)d_in[16];
    const float* Wj = (const float*)d_in[17];
    const float* bj = (const float*)d_in[18];
    const float* Wp0 = (const float*)d_in[19];
    const float* bp0 = (const float*)d_in[20];

    float* ws = (float*)d_ws;
    float* out = (float*)d_out;
    float* out_em = out;                     // [16][128][64]
    float* out_tr = out + 131072;            // [16][128][128]
    float* out_tl = out + 131072 + 262144;   // [16][128][128]

    // 1) fused zero + all pre-LSTM converts (XF, WXFW, WXBW, Wproj_t A-frags, nnW B-frags)
    mega_prep_k<<<1380, 256, 0, stream>>>((float4*)ws, ZERO_N / 4,
                                          emb, targets, (uint4*)(ws + O_XF),
                                          Wx_fw, (uint4*)(ws + O_WXFW),
                                          Wx_bw, (uint4*)(ws + O_WXBW),
                                          Wproj_t, (uint4*)(ws + O_WPTAF),
                                          nnW, (uint4*)(ws + O_NNWF));

    // 2) gx (both dirs) + W_comb = Wproj_t @ nnW (one launch)
    gxw_gemm_k<<<dim3(36, 8), 256, 0, stream>>>((uint4*)(ws + O_XF), (uint4*)(ws + O_WXFW),
                                                (uint4*)(ws + O_WXBW), b_fw, b_bw, ws + O_GX,
                                                (uint4*)(ws + O_WPTAF), (uint4*)(ws + O_NNWF),
                                                ws + O_WCOMB);

    // 3) persistent LSTM + fillers + 224 clock-hold spinner blocks
    lstm_fused_k<<<1021, 256, 0, stream>>>(Wh_fw, Wh_bw, ws + O_GX, lengths,
                                           (unsigned*)(ws + O_HBUF), (unsigned*)(ws + O_HCATF),
                                           (unsigned*)(ws + O_SLOTS),
                                           Wv, emb, tnull, nnW, nnb, bv,
                                           ws + O_NS, ws + O_NULLD,
                                           sources, ws + O_WVC,
                                           Wproj_e, (uint4*)(ws + O_WPEF),
                                           ws + O_WCOMB, (uint4*)(ws + O_WCOMBF));

    // 4) projections: ts (plain) + tt (tanh, via W_comb associativity) — one launch
    projts_k<<<dim3(8, 8), 256, 0, stream>>>((uint4*)(ws + O_HCATF), (uint4*)(ws + O_WPEF),
                                             (uint4*)(ws + O_WCOMBF), nnb,
                                             ws + O_TS, ws + O_TT);

    // 5) ts -> bf16 A-frags + transition (both small-LDS, both depend only on projts)
    convtr_k<<<1280, 256, 0, stream>>>(ws + O_TS, (uint4*)(ws + O_TSF),
                                       ws + O_TT, Wj, bj, Wp0, bp0, out_tr, out_tl);

    // 6) phaseA (denominators), standalone 128 KB-LDS kernel
    phaseA_mfma_k<<<250, 256, 0, stream>>>((const uint4*)(ws + O_TSF), Wv, bv, ws + O_DENOM);

    // 7) emission output (coalesced reads of pre-gathered Wv columns)
    emission_k<<<dim3(8, 16), 512, 0, stream>>>(ws + O_TS, ws + O_WVC, bv, sources, ws + O_NS,
                                                ws + O_DENOM, ws + O_NULLD, out_em);
}

// Round 13
// 891.596 us; speedup vs baseline: 1.0121x; 1.0121x over previous
//
#include <hip/hip_runtime.h>
#include <hip/hip_bf16.h>
#include <math.h>

// Shapes (fixed by the reference)
#define Bn 16
#define Sn 64
#define Tn 64
#define En 256
#define Hn 512
#define VS 32000
#define Jn 201
#define Mn 100

// Workspace layout (float offsets)
#define O_HCATF  0                      // hcat bf16 A-frags [64 mt][32 ks][64 lane][8] = 524288 fl
#define O_DENOM  524288                 // [1024]
#define O_NULLD  525312                 // [64] ([0] live; [32..63] spinner DCE-defeat scratch)
#define O_SLOTS  525376                 // 32 slots x 64 uints (256B apart)
#define O_HBUF   527424                 // u32 [2 pp][2 dir][16 b][256] = 32768 fl
#define ZERO_N   560192
#define O_NS     560192                 // [512]
#define O_TS     560704                 // [1024][512] fp32; pre-LSTM holds W_comb fp32, proj overwrites with ts
#define O_WCOMB  560704                 // alias: W_comb = Wproj_t @ nnW fp32 [1024][512]
#define O_TSF    1084992                // ts A-frags bf16 -> 262144 fl -> 1347136
#define O_WCOMBF 1347136                // W_comb B-frags -> 262144 fl -> 1609280
#define O_WPTAF  1609280                // Wproj_t A-frags -> 131072 -> 1740352
#define O_TT     1740352                // [1024][512] fp32 -> 2264640
#define O_XF     2264640                // emb-gather A-frags -> 131072 -> 2395712 (dead after gx launch)
#define O_WVC    2264640                // gathered Wv columns [1024][512] fp32 (filler-written during LSTM)
#define O_WXFW   2395712                // Wx_fw B-frags -> 262144 -> 2657856 (dead after gx launch)
#define O_WXBW   2657856                // Wx_bw B-frags -> 262144 -> 2920000 (dead after gx launch)
#define O_WPEF   2920000                // Wproj_e B-frags -> 262144 -> 3182144 (filler-written during LSTM)
#define O_NNWF   3313216                // nnW B-frags -> 65536 -> 3378752 (mega_prep-written, read by gxw)
#define O_GX     3378752                // [2][1024][2048] fp32 -> 7573056 (LSTM-live)

typedef __attribute__((ext_vector_type(8))) short short8;
typedef __attribute__((ext_vector_type(4))) float f32x4;

__device__ __forceinline__ float sigf(float x) { return 1.0f / (1.0f + expf(-x)); }
__device__ __forceinline__ unsigned short tobf(float x) {
    __hip_bfloat16 h = __float2bfloat16(x);
    return *reinterpret_cast<unsigned short*>(&h);
}

// ---------------- device conversion bodies ----------------
__device__ __forceinline__ void dconvA(const float* __restrict__ A, uint4* __restrict__ out,
                                       int K, const int* __restrict__ gidx, int g) {
    int Kd = K >> 5;
    int lane = g & 63, t = g >> 6;
    int ks = t % Kd, mt = t / Kd;
    int m = mt * 16 + (lane & 15);
    int k0 = ks * 32 + (lane >> 4) * 8;
    const float* p = (gidx ? A + (size_t)gidx[m] * K : A + (size_t)m * K) + k0;
    float4 f0 = *(const float4*)(p);
    float4 f1 = *(const float4*)(p + 4);
    unsigned short u[8] = {tobf(f0.x), tobf(f0.y), tobf(f0.z), tobf(f0.w),
                           tobf(f1.x), tobf(f1.y), tobf(f1.z), tobf(f1.w)};
    out[g] = *(uint4*)u;
}

__device__ __forceinline__ void dconvB(const float* __restrict__ B, uint4* __restrict__ out,
                                       int N, int K, int g) {
    int Kd = K >> 5;
    int lane = g & 63, t = g >> 6;
    int ks = t % Kd, nt = t / Kd;
    int n = nt * 16 + (lane & 15);
    int k0 = ks * 32 + (lane >> 4) * 8;
    const float* p = B + (size_t)k0 * N + n;
    unsigned short u[8];
#pragma unroll
    for (int j = 0; j < 8; j++) u[j] = tobf(p[(size_t)j * N]);
    out[g] = *(uint4*)u;
}

// ---------------- fused prolog: zero + all pre-LSTM converts ----------------
__global__ __launch_bounds__(256) void mega_prep_k(float4* __restrict__ zdst, int zn4,
                                                   const float* __restrict__ emb,
                                                   const int* __restrict__ targets,
                                                   uint4* __restrict__ xf,
                                                   const float* __restrict__ wxfw, uint4* __restrict__ wxfwf,
                                                   const float* __restrict__ wxbw, uint4* __restrict__ wxbwf,
                                                   const float* __restrict__ wpt, uint4* __restrict__ wptaf,
                                                   const float* __restrict__ nnw, uint4* __restrict__ nnwf) {
    int blk = blockIdx.x, tid = threadIdx.x;
    if (blk < 548) {
        int i = blk * 256 + tid;
        if (i < zn4) zdst[i] = make_float4(0.f, 0.f, 0.f, 0.f);
    } else if (blk < 676) {
        dconvA(emb, xf, 256, targets, (blk - 548) * 256 + tid);
    } else if (blk < 932) {
        dconvB(wxfw, wxfwf, 2048, 256, (blk - 676) * 256 + tid);
    } else if (blk < 1188) {
        dconvB(wxbw, wxbwf, 2048, 256, (blk - 932) * 256 + tid);
    } else if (blk < 1316) {
        dconvA(wpt, wptaf, 256, nullptr, (blk - 1188) * 256 + tid);   // Wproj_t A-frags [1024][256]
    } else {
        dconvB(nnw, nnwf, 512, 256, (blk - 1316) * 256 + tid);        // nnW B-frags [256][512]
    }
}

// ---------------- generic MFMA GEMM body: C = act(A@B + bias), fp32 out ----------------
template <int ACT>
__device__ __forceinline__ void gemm_body(const uint4* __restrict__ af,
                                          const uint4* __restrict__ bf,
                                          const float* __restrict__ bias,
                                          float* __restrict__ C, int N, int Kd,
                                          int bx, int by) {
    int tid = threadIdx.x, w = tid >> 6, lane = tid & 63;
    int ntb = bx * 8 + w * 2;
    int mtb = by * 8;
    f32x4 acc[8][2];
#pragma unroll
    for (int i = 0; i < 8; i++)
#pragma unroll
        for (int j = 0; j < 2; j++) acc[i][j] = 0.0f;
    for (int ks = 0; ks < Kd; ++ks) {
        uint4 b0 = bf[(size_t)(ntb * Kd + ks) * 64 + lane];
        uint4 b1 = bf[(size_t)((ntb + 1) * Kd + ks) * 64 + lane];
#pragma unroll
        for (int i = 0; i < 8; i++) {
            uint4 a = af[(size_t)((mtb + i) * Kd + ks) * 64 + lane];
            acc[i][0] = __builtin_amdgcn_mfma_f32_16x16x32_bf16(
                *reinterpret_cast<short8*>(&a), *reinterpret_cast<short8*>(&b0), acc[i][0], 0, 0, 0);
            acc[i][1] = __builtin_amdgcn_mfma_f32_16x16x32_bf16(
                *reinterpret_cast<short8*>(&a), *reinterpret_cast<short8*>(&b1), acc[i][1], 0, 0, 0);
        }
    }
    int n0 = ntb * 16 + (lane & 15);
    int q = lane >> 4;
    float bs0 = bias ? bias[n0] : 0.f;
    float bs1 = bias ? bias[n0 + 16] : 0.f;
#pragma unroll
    for (int i = 0; i < 8; i++)
#pragma unroll
        for (int r = 0; r < 4; r++) {
            int m = (mtb + i) * 16 + q * 4 + r;
            float v0 = acc[i][0][r] + bs0;
            float v1 = acc[i][1][r] + bs1;
            if (ACT == 1) { v0 = tanhf(v0); v1 = tanhf(v1); }
            C[(size_t)m * N + n0] = v0;
            C[(size_t)m * N + n0 + 16] = v1;
        }
}

// merged: both gx GEMMs + W_comb GEMM
__global__ __launch_bounds__(256) void gxw_gemm_k(const uint4* __restrict__ xf,
                                                  const uint4* __restrict__ wxfwf,
                                                  const uint4* __restrict__ wxbwf,
                                                  const float* __restrict__ b_fw,
                                                  const float* __restrict__ b_bw,
                                                  float* __restrict__ gx,
                                                  const uint4* __restrict__ wptaf,
                                                  const uint4* __restrict__ nnwf,
                                                  float* __restrict__ wcomb) {
    int bx = blockIdx.x;
    if (bx < 16)      gemm_body<0>(xf, wxfwf, b_fw, gx, 2048, 8, bx, blockIdx.y);
    else if (bx < 32) gemm_body<0>(xf, wxbwf, b_bw, gx + 2097152, 2048, 8, bx - 16, blockIdx.y);
    else              gemm_body<0>(wptaf, nnwf, nullptr, wcomb, 512, 8, bx - 32, blockIdx.y);
}

// merged: ts = hcat@Wproj_e (plain) and tt = tanh(hcat@W_comb + nnb)
__global__ __launch_bounds__(256) void projts_k(const uint4* __restrict__ hcatf,
                                                const uint4* __restrict__ wpef,
                                                const uint4* __restrict__ wcombf,
                                                const float* __restrict__ nnb,
                                                float* __restrict__ ts,
                                                float* __restrict__ tt) {
    int bx = blockIdx.x;
    if (bx < 4) gemm_body<0>(hcatf, wpef, nullptr, ts, 512, 32, bx, blockIdx.y);
    else        gemm_body<1>(hcatf, wcombf, nnb, tt, 512, 32, bx - 4, blockIdx.y);
}

// ---------------- fused persistent LSTM + fillers + FABRIC-streaming spinners ----------------
// blocks    0..31 : r1's proven barrier-protocol LSTM (verbatim).
// blocks   32..156: null state + null denominator.
// blocks  157..284: gather emission's Wv columns into O_WVC.
// blocks  285..540: Wproj_e -> B-frags (O_WPEF).
// blocks  541..796: W_comb -> B-frags (O_WCOMBF).
// blocks 797..1020: MEMORY STREAMERS — continuously read the LLC-resident 16 MB gx
//   region to keep the DATA FABRIC / LLC clock domain active (r11 falsified SCLK
//   throttle via FMA spinners — zero fabric traffic; the exchange path is entirely
//   fabric+LLC, governed by FCLK/MCLK). Flag polled once per 256 KB chunk from tid 0
//   only (fixes r11's flag-line contention). Reads only; DCE defeated via impossible
//   conditional store to nulld[32..63] (unused scratch).
__global__ __launch_bounds__(256, 1) void lstm_fused_k(const float* __restrict__ wh_fw,
                                                       const float* __restrict__ wh_bw,
                                                       const float* __restrict__ gx,
                                                       const int* __restrict__ lengths,
                                                       unsigned* __restrict__ hbuf32,
                                                       unsigned* __restrict__ hcat32,
                                                       unsigned* __restrict__ slots,
                                                       const float* __restrict__ Wv,
                                                       const float* __restrict__ emb,
                                                       const int* __restrict__ tnull,
                                                       const float* __restrict__ nnW,
                                                       const float* __restrict__ nnb,
                                                       const float* __restrict__ bv,
                                                       float* __restrict__ ns,
                                                       float* __restrict__ nd,
                                                       const int* __restrict__ sources,
                                                       float* __restrict__ wvc,
                                                       const float* __restrict__ wpe, uint4* __restrict__ wpef,
                                                       const float* __restrict__ wcomb, uint4* __restrict__ wcombf) {
    int blk = blockIdx.x;
    int tid = threadIdx.x;

    if (blk >= 797) {
        // ---- fabric/LLC streamer (see header comment) ----
        __shared__ unsigned doneS;
        const float4* src = (const float4*)gx;            // 4M floats = 1M float4 (16 MB)
        float acc = 0.f;
        unsigned base = (unsigned)(blk - 797) * 4681u;    // spread start offsets
        for (;;) {
            if (tid == 0)
                doneS = __hip_atomic_load(&slots[0], __ATOMIC_RELAXED, __HIP_MEMORY_SCOPE_AGENT);
            __syncthreads();
            if (doneS >= 63u) break;
#pragma unroll 4
            for (int it = 0; it < 64; ++it) {
                unsigned idx = (base + (unsigned)it * 256u + (unsigned)tid) & 1048575u;
                float4 v = src[idx];
                acc += v.x + v.y + v.z + v.w;
            }
            base = (base + 16384u) & 1048575u;
            __syncthreads();
        }
        if (acc == 123.456789f) nd[32 + (blk & 31)] = acc;   // unreachable; defeats DCE
        return;
    }
    if (blk >= 541) {                 // W_comb -> B-frags (N=512, K=1024)
        dconvB(wcomb, wcombf, 512, 1024, (blk - 541) * 256 + tid);
        return;
    }
    if (blk >= 285) {                 // Wproj_e B-frags
        dconvB(wpe, wpef, 512, 1024, (blk - 285) * 256 + tid);
        return;
    }
    if (blk >= 157) {
        // ---- gather emission's Wv columns: wvc[ci][k] = Wv[k][sources[ci]] ----
        int cb = blk - 157;           // 0..127, 8 columns each
#pragma unroll
        for (int cc = 0; cc < 8; ++cc) {
            int ci = cb * 8 + cc;
            int c = sources[ci];
            float v0 = Wv[(size_t)tid * VS + c];
            float v1 = Wv[(size_t)(tid + 256) * VS + c];
            wvc[(size_t)ci * 512 + tid] = v0;
            wvc[(size_t)ci * 512 + 256 + tid] = v1;
        }
        return;
    }
    if (blk >= 32) {
        // ---- null state + denom ----
        __shared__ float xn[En];
        __shared__ float nsl[Hn];
        __shared__ float red[4];
        int bid = blk - 32;
        xn[tid] = emb[(size_t)tnull[0] * En + tid];
        __syncthreads();
#pragma unroll
        for (int hh = 0; hh < 2; hh++) {
            int h = tid + hh * 256;
            float a = nnb[h];
            for (int e = 0; e < En; e++) a += xn[e] * nnW[(size_t)e * Hn + h];
            float v = tanhf(a);
            nsl[h] = v;
            if (bid == 0) ns[h] = v;
        }
        __syncthreads();
        int v = bid * 256 + tid;
        float a = bv[v];
        for (int k = 0; k < Hn; k++) a += nsl[k] * Wv[(size_t)k * VS + v];
        float e = expf(a);
        for (int o = 1; o < 64; o <<= 1) e += __shfl_xor(e, o);
        if ((tid & 63) == 0) red[tid >> 6] = e;
        __syncthreads();
        if (tid == 0) atomicAdd(nd, red[0] + red[1] + red[2] + red[3]);
        return;
    }

    // ---- r1 persistent bidirectional LSTM (verbatim) ----
    __shared__ uint4 whf[8192];       // 128 KB B-frags
    __shared__ float raw[32][129];
    __shared__ int lenS[16];
    int dir = blk >> 4;
    int u0 = (blk & 15) * 32;
    const float* wh = dir ? wh_bw : wh_fw;
    if (tid < 16) lenS[tid] = lengths[tid];

    // one-time Wh -> bf16 B-frag staging
    for (int chunk = 0; chunk < 16; ++chunk) {
#pragma unroll
        for (int it = 0; it < 16; ++it) {
            int li = it * 256 + tid;
            int kl = li >> 7, c = li & 127;
            int g = c >> 5, ub = c & 31;
            raw[kl][c] = wh[(size_t)(chunk * 32 + kl) * 2048 + g * 512 + u0 + ub];
        }
        __syncthreads();
#pragma unroll
        for (int it = 0; it < 2; ++it) {
            int idx = tid * 2 + it;
            int w = idx >> 7, t = (idx >> 6) & 1, lane = idx & 63;
            int n = lane & 15, uu = n >> 1, p = n & 1;
            int cc = (t * 2 + p) * 32 + w * 8 + uu;
            int kb = (lane >> 4) * 8;
            unsigned short u8[8];
#pragma unroll
            for (int j = 0; j < 8; j++) u8[j] = tobf(raw[kb + j][cc]);
            whf[((w * 2 + t) * 16 + chunk) * 64 + lane] = *(uint4*)u8;
        }
        __syncthreads();
    }

    int wv = tid >> 6, lane = tid & 63;
    int n = lane & 15, uu = n >> 1, q = lane >> 4;
    int u = u0 + wv * 8 + uu;
    float creg[4] = {0.f, 0.f, 0.f, 0.f};
    unsigned short hbf[4] = {0, 0, 0, 0};

    for (int s = 0; s < 64; ++s) {
        // ---- gx prefetch (normal cached loads, issued first) ----
        float gxi[4], gxj[4], gxf[4], gxo[4];
#pragma unroll
        for (int r = 0; r < 4; r++) {
            int b = q * 4 + r;
            int len = lenS[b];
            int tc = dir ? (len - 1 - s) : s;
            tc = tc < 0 ? 0 : tc;
            const float* gp = gx + (size_t)dir * 2097152 + (size_t)(b * 64 + tc) * 2048 + u;
            gxi[r] = gp[0]; gxj[r] = gp[512]; gxf[r] = gp[1024]; gxo[r] = gp[1536];
        }
        // ---- A-frags: bypass-atomic u64 loads of h (b = n, k = units) ----
        const unsigned long long* hb64 =
            (const unsigned long long*)(hbuf32 + (((s & 1) * 2 + dir) * 16) * 256);
        unsigned long long h64[32];
#pragma unroll
        for (int ks = 0; ks < 16; ks++) {
            int idx = n * 128 + ks * 8 + q * 2;
            h64[2 * ks] = __hip_atomic_load(hb64 + idx, __ATOMIC_RELAXED, __HIP_MEMORY_SCOPE_AGENT);
            h64[2 * ks + 1] = __hip_atomic_load(hb64 + idx + 1, __ATOMIC_RELAXED, __HIP_MEMORY_SCOPE_AGENT);
        }
        // ---- MFMA ----
        f32x4 acc0 = {0.f, 0.f, 0.f, 0.f}, acc1 = {0.f, 0.f, 0.f, 0.f};
#pragma unroll
        for (int ks = 0; ks < 16; ks++) {
            unsigned long long av[2] = {h64[2 * ks], h64[2 * ks + 1]};
            short8 a = *reinterpret_cast<short8*>(av);
            uint4 b0 = whf[((wv * 2 + 0) * 16 + ks) * 64 + lane];
            uint4 b1 = whf[((wv * 2 + 1) * 16 + ks) * 64 + lane];
            acc0 = __builtin_amdgcn_mfma_f32_16x16x32_bf16(a, *reinterpret_cast<short8*>(&b0), acc0, 0, 0, 0);
            acc1 = __builtin_amdgcn_mfma_f32_16x16x32_bf16(a, *reinterpret_cast<short8*>(&b1), acc1, 0, 0, 0);
        }
        // ---- gates (even lanes i/f in acc0/acc1; odd lanes j/o of same unit) ----
#pragma unroll
        for (int r = 0; r < 4; r++) {
            float jvv = __shfl_xor(acc0[r], 1);
            float ovv = __shfl_xor(acc1[r], 1);
            int b = q * 4 + r;
            int len = lenS[b];
            float gi = acc0[r] + gxi[r];
            float gj = jvv + gxj[r];
            float gf = acc1[r] + gxf[r];
            float go = ovv + gxo[r];
            float cn = sigf(gf + 1.0f) * creg[r] + sigf(gi) * tanhf(gj);
            float hn = sigf(go) * tanhf(cn);
            if (s < len) { creg[r] = cn; hbf[r] = tobf(hn); }
        }
        // ---- pack unit pairs and store (lanes n%4==0 own units u,u+1) ----
#pragma unroll
        for (int r = 0; r < 4; r++) {
            unsigned self = hbf[r];
            unsigned part = (unsigned)__shfl_xor((int)self, 2) & 0xffffu;
            if ((n & 3) == 0) {
                unsigned pk = self | (part << 16);
                int b = q * 4 + r;
                __hip_atomic_store(
                    hbuf32 + ((((s + 1) & 1) * 2 + dir) * 16 + b) * 256 + (u >> 1), pk,
                    __ATOMIC_RELAXED, __HIP_MEMORY_SCOPE_AGENT);
                int len = lenS[b];
                if (s < len) {
                    int tin = dir ? (len - 1 - s) : s;
                    int row = b * 64 + tin, col = dir * 512 + u;
                    int mt = row >> 4, ksx = col >> 5;
                    int lanep = (row & 15) | (((col >> 3) & 3) << 4);
                    hcat32[(size_t)(((mt * 32 + ksx) * 64 + lanep) * 4) + ((col & 7) >> 1)] = pk;
                }
            }
        }
        if (s == 63) break;
        __syncthreads();  // vmcnt(0) drain: h stores at coherence point before flag
        if (tid == 0)     // RELAXED flag: no per-step buffer_wbl2
            __hip_atomic_store(&slots[blk * 64], (unsigned)(s + 1), __ATOMIC_RELAXED,
                               __HIP_MEMORY_SCOPE_AGENT);
        if (tid < 16) {
            while (__hip_atomic_load(&slots[(dir * 16 + tid) * 64], __ATOMIC_RELAXED,
                                     __HIP_MEMORY_SCOPE_AGENT) < (unsigned)(s + 1)) {
                __builtin_amdgcn_s_sleep(1);
            }
        }
        __syncthreads();
    }
}

// ---------------- convA (ts->tsf, blocks 0..255) + transition (blocks 256..1279) ----------------
__global__ __launch_bounds__(256) void convtr_k(const float* __restrict__ ts,
                                                uint4* __restrict__ tsf,
                                                const float* __restrict__ tt,
                                                const float* __restrict__ Wj,
                                                const float* __restrict__ bj,
                                                const float* __restrict__ Wp0,
                                                const float* __restrict__ bp0,
                                                float* __restrict__ trans,
                                                float* __restrict__ tlog) {
    __shared__ float ttl[512];
    __shared__ float jrow[Jn], ljrow[Jn];
    __shared__ float sred[256];
    __shared__ float p0_s, lp0_s;
    int blk = blockIdx.x;
    int tid = threadIdx.x;
    if (blk < 256) {
        dconvA(ts, tsf, 512, nullptr, blk * 256 + tid);
        return;
    }
    int tb = blk - 256;
    int b = tb >> 6, i = tb & 63;
    {
        const float* trr = tt + (size_t)tb * 512;
        if (tid < 128) *(float4*)&ttl[tid * 4] = *(const float4*)(trr + tid * 4);
    }
    __syncthreads();
    bool isj = tid < Jn;
    bool isp = tid == Jn;
    float l = 0.f;
    if (isj || isp) {
        const float* wb = isj ? (Wj + tid) : Wp0;
        int stride = isj ? Jn : 1;
        float a = isj ? bj[tid] : bp0[0];
        for (int k = 0; k < 512; k++) a += ttl[k] * wb[(size_t)k * stride];
        l = a;
    }
    sred[tid] = isj ? l : -1e30f;
    __syncthreads();
    for (int o = 128; o > 0; o >>= 1) {
        if (tid < o) sred[tid] = fmaxf(sred[tid], sred[tid + o]);
        __syncthreads();
    }
    float m = sred[0];
    __syncthreads();
    float ex = isj ? expf(l - m) : 0.f;
    sred[tid] = ex;
    __syncthreads();
    for (int o = 128; o > 0; o >>= 1) {
        if (tid < o) sred[tid] += sred[tid + o];
        __syncthreads();
    }
    float S = sred[0];
    if (isj) {
        jrow[tid] = ex / S;
        ljrow[tid] = (l - m) - logf(S);
    }
    if (isp) {
        float pv = 1.f / (1.f + expf(-l));
        p0_s = pv;
        lp0_s = logf(pv);
    }
    __syncthreads();
    if (tid < 128) {
        int j = tid;
        float tv, lv;
        if (j < 64) {
            int id = Mn + j - i;
            tv = jrow[id];
            lv = ljrow[id];
        } else {
            bool dg = (j - 64) == i;
            tv = dg ? p0_s : 0.f;
            lv = dg ? lp0_s : 0.f;
        }
        size_t r1 = (size_t)(b * 128 + i) * 128 + j;
        size_t r2 = (size_t)(b * 128 + 64 + i) * 128 + j;
        trans[r1] = tv;
        trans[r2] = tv;
        tlog[r1] = lv;
        tlog[r2] = lv;
    }
}

// ---------------- Phase A: MFMA bf16 row-sum-of-exp, Wv converted in-LDS (standalone) ----------------
__global__ __launch_bounds__(256) void phaseA_mfma_k(const uint4* __restrict__ tsb,
                                                     const float* __restrict__ Wv,
                                                     const float* __restrict__ bv,
                                                     float* __restrict__ denom) {
    __shared__ uint4 wls[8192];      // 128 KB: [8 tiles][16 ks][64 lane]
    __shared__ float redL[4][128];
    int tid = threadIdx.x;
    int wave = tid >> 6, lane = tid & 63;
    for (int it = 0; it < 32; ++it) {
        int g = it * 256 + tid;
        int gl = g & 63, t = g >> 6;
        int ks = t & 15, tl = t >> 4;
        int nt = blockIdx.x * 8 + tl;
        int nn = nt * 16 + (gl & 15);
        int k0 = ks * 32 + (gl >> 4) * 8;
        const float* p = Wv + (size_t)k0 * VS + nn;
        unsigned short u[8];
#pragma unroll
        for (int j = 0; j < 8; j++) u[j] = tobf(p[(size_t)j * VS]);
        wls[g] = *(uint4*)u;
    }
    __syncthreads();

    int ntbase = blockIdx.x * 8 + wave * 2;
    float bv0 = bv[ntbase * 16 + (lane & 15)];
    float bv1 = bv[(ntbase + 1) * 16 + (lane & 15)];
    int q = lane >> 4;
    for (int mc = 0; mc < 8; ++mc) {
        f32x4 acc[8][2];
#pragma unroll
        for (int i = 0; i < 8; i++)
#pragma unroll
            for (int j = 0; j < 2; j++) acc[i][j] = 0.0f;
#pragma unroll 4
        for (int ks = 0; ks < 16; ++ks) {
            short8 a[8], b[2];
#pragma unroll
            for (int i = 0; i < 8; i++) {
                int mt = mc * 8 + i;
                uint4 t = tsb[(size_t)(mt * 16 + ks) * 64 + lane];
                a[i] = *reinterpret_cast<short8*>(&t);
            }
#pragma unroll
            for (int j = 0; j < 2; j++) {
                uint4 t = wls[((wave * 2 + j) * 16 + ks) * 64 + lane];
                b[j] = *reinterpret_cast<short8*>(&t);
            }
#pragma unroll
            for (int i = 0; i < 8; i++)
#pragma unroll
                for (int j = 0; j < 2; j++)
                    acc[i][j] = __builtin_amdgcn_mfma_f32_16x16x32_bf16(a[i], b[j], acc[i][j], 0, 0, 0);
        }
#pragma unroll
        for (int i = 0; i < 8; i++) {
#pragma unroll
            for (int r = 0; r < 4; r++) {
                float e = __expf(acc[i][0][r] + bv0) + __expf(acc[i][1][r] + bv1);
                e += __shfl_xor(e, 1);
                e += __shfl_xor(e, 2);
                e += __shfl_xor(e, 4);
                e += __shfl_xor(e, 8);
                if ((lane & 15) == 0) redL[wave][i * 16 + q * 4 + r] = e;
            }
        }
        __syncthreads();
        if (tid < 128) {
            float v = redL[0][tid] + redL[1][tid] + redL[2][tid] + redL[3][tid];
            atomicAdd(&denom[mc * 128 + tid], v);
        }
        __syncthreads();
    }
}

// ---------------- emission assembly (reads pre-gathered Wv columns) ----------------
__global__ __launch_bounds__(512) void emission_k(const float* __restrict__ ts,
                                                  const float* __restrict__ wvc,
                                                  const float* __restrict__ bv,
                                                  const int* __restrict__ sources,
                                                  const float* __restrict__ ns,
                                                  const float* __restrict__ denom,
                                                  const float* __restrict__ nulld,
                                                  float* __restrict__ em) {
    __shared__ float colv[512];
    __shared__ float red[64][9];
    __shared__ float red2[8];
    __shared__ float env_s, bvc_s;
    int b = blockIdx.y, sc = blockIdx.x;
    int tid = threadIdx.x;
    for (int qq = 0; qq < 8; ++qq) {
        int s = sc * 8 + qq;
        int ci = b * 64 + s;
        __syncthreads();
        colv[tid] = wvc[(size_t)ci * 512 + tid];
        if (tid == 0) bvc_s = bv[sources[ci]];
        __syncthreads();
        int r = tid & 63, ksl = tid >> 6;
        const float* tr = ts + (size_t)(b * 64 + r) * 512 + ksl * 64;
        float p = 0.f;
#pragma unroll
        for (int k4 = 0; k4 < 16; k4++) {
            float4 t4 = *(const float4*)(tr + k4 * 4);
            float4 c4 = *(const float4*)&colv[ksl * 64 + k4 * 4];
            p += t4.x * c4.x + t4.y * c4.y + t4.z * c4.z + t4.w * c4.w;
        }
        red[r][ksl] = p;
        if (tid < 8) {
            float pn = 0.f;
#pragma unroll
            for (int k4 = 0; k4 < 16; k4++) {
                float4 n4 = *(const float4*)(ns + tid * 64 + k4 * 4);
                float4 c4 = *(const float4*)&colv[tid * 64 + k4 * 4];
                pn += n4.x * c4.x + n4.y * c4.y + n4.z * c4.z + n4.w * c4.w;
            }
            red2[tid] = pn;
        }
        __syncthreads();
        if (tid < 64) {
            float dot = red[tid][0] + red[tid][1] + red[tid][2] + red[tid][3] +
                        red[tid][4] + red[tid][5] + red[tid][6] + red[tid][7];
            float ew = expf(dot + bvc_s) / denom[b * 64 + tid];
            em[(size_t)(b * 128 + tid) * 64 + s] = ew;
        } else if (tid == 64) {
            float dn = red2[0] + red2[1] + red2[2] + red2[3] +
                       red2[4] + red2[5] + red2[6] + red2[7];
            env_s = expf(dn + bvc_s) / nulld[0];
        }
        __syncthreads();
        if (tid < 64) em[(size_t)(b * 128 + 64 + tid) * 64 + s] = env_s;
    }
}

extern "C" void kernel_launch(void* const* d_in, const int* in_sizes, int n_in,
                              void* d_out, int out_size, void* d_ws, size_t ws_size,
                              hipStream_t stream) {
    const int* sources = (const int*)d_in[0];
    const int* targets = (const int*)d_in[1];
    const int* tnull = (const int*)d_in[2];
    const int* lengths = (const int*)d_in[3];
    const float* emb = (const float*)d_in[4];
    const float* nnW = (const float*)d_in[5];
    const float* nnb = (const float*)d_in[6];
    const float* Wx_fw = (const float*)d_in[7];
    const float* Wh_fw = (const float*)d_in[8];
    const float* b_fw = (const float*)d_in[9];
    const float* Wx_bw = (const float*)d_in[10];
    const float* Wh_bw = (const float*)d_in[11];
    const float* b_bw = (const float*)d_in[12];
    const float* Wproj_e = (const float*)d_in[13];
    const float* Wv = (const float*)d_in[14];
    const float* bv = (const float*)d_in[15];
    const float* Wproj_t = (const float*)d_in[16];
    const float* Wj = (const float*)d_in[17];
    const float* bj = (const float*)d_in[18];
    const float* Wp0 = (const float*)d_in[19];
    const float* bp0 = (const float*)d_in[20];

    float* ws = (float*)d_ws;
    float* out = (float*)d_out;
    float* out_em = out;                     // [16][128][64]
    float* out_tr = out + 131072;            // [16][128][128]
    float* out_tl = out + 131072 + 262144;   // [16][128][128]

    // 1) fused zero + all pre-LSTM converts (XF, WXFW, WXBW, Wproj_t A-frags, nnW B-frags)
    mega_prep_k<<<1380, 256, 0, stream>>>((float4*)ws, ZERO_N / 4,
                                          emb, targets, (uint4*)(ws + O_XF),
                                          Wx_fw, (uint4*)(ws + O_WXFW),
                                          Wx_bw, (uint4*)(ws + O_WXBW),
                                          Wproj_t, (uint4*)(ws + O_WPTAF),
                                          nnW, (uint4*)(ws + O_NNWF));

    // 2) gx (both dirs) + W_comb = Wproj_t @ nnW (one launch)
    gxw_gemm_k<<<dim3(36, 8), 256, 0, stream>>>((uint4*)(ws + O_XF), (uint4*)(ws + O_WXFW),
                                                (uint4*)(ws + O_WXBW), b_fw, b_bw, ws + O_GX,
                                                (uint4*)(ws + O_WPTAF), (uint4*)(ws + O_NNWF),
                                                ws + O_WCOMB);

    // 3) persistent LSTM + fillers + 224 fabric/LLC-streaming spinner blocks
    lstm_fused_k<<<1021, 256, 0, stream>>>(Wh_fw, Wh_bw, ws + O_GX, lengths,
                                           (unsigned*)(ws + O_HBUF), (unsigned*)(ws + O_HCATF),
                                           (unsigned*)(ws + O_SLOTS),
                                           Wv, emb, tnull, nnW, nnb, bv,
                                           ws + O_NS, ws + O_NULLD,
                                           sources, ws + O_WVC,
                                           Wproj_e, (uint4*)(ws + O_WPEF),
                                           ws + O_WCOMB, (uint4*)(ws + O_WCOMBF));

    // 4) projections: ts (plain) + tt (tanh, via W_comb associativity) — one launch
    projts_k<<<dim3(8, 8), 256, 0, stream>>>((uint4*)(ws + O_HCATF), (uint4*)(ws + O_WPEF),
                                             (uint4*)(ws + O_WCOMBF), nnb,
                                             ws + O_TS, ws + O_TT);

    // 5) ts -> bf16 A-frags + transition (both small-LDS, both depend only on projts)
    convtr_k<<<1280, 256, 0, stream>>>(ws + O_TS, (uint4*)(ws + O_TSF),
                                       ws + O_TT, Wj, bj, Wp0, bp0, out_tr, out_tl);

    // 6) phaseA (denominators), standalone 128 KB-LDS kernel
    phaseA_mfma_k<<<250, 256, 0, stream>>>((const uint4*)(ws + O_TSF), Wv, bv, ws + O_DENOM);

    // 7) emission output (coalesced reads of pre-gathered Wv columns)
    emission_k<<<dim3(8, 16), 512, 0, stream>>>(ws + O_TS, ws + O_WVC, bv, sources, ws + O_NS,
                                                ws + O_DENOM, ws + O_NULLD, out_em);
}

// Round 14
// 810.021 us; speedup vs baseline: 1.1141x; 1.1007x over previous
//
#include <hip/hip_runtime.h>
#include <hip/hip_bf16.h>
#include <math.h>

// Shapes (fixed by the reference)
#define Bn 16
#define Sn 64
#define Tn 64
#define En 256
#define Hn 512
#define VS 32000
#define Jn 201
#define Mn 100

// Workspace layout (float offsets)
#define O_HCATF  0                      // hcat bf16 A-frags [64 mt][32 ks][64 lane][8] = 524288 fl
#define O_DENOM  524288                 // [1024]
#define O_NULLD  525312                 // [64]
#define O_SLOTS  525376                 // 32 slots x 64 uints (256B apart)
#define O_HBUF   527424                 // u32 [2 pp][2 dir][16 b][256] = 32768 fl
#define ZERO_N   560192
#define O_NS     560192                 // [512]
#define O_TS     560704                 // [1024][512] fp32; pre-LSTM holds W_comb fp32, proj overwrites with ts
#define O_WCOMB  560704                 // alias: W_comb = Wproj_t @ nnW fp32 [1024][512]
#define O_TSF    1084992                // ts A-frags bf16 -> 262144 fl -> 1347136
#define O_WCOMBF 1347136                // W_comb B-frags -> 262144 fl -> 1609280
#define O_WPTAF  1609280                // Wproj_t A-frags -> 131072 -> 1740352
#define O_TT     1740352                // [1024][512] fp32 -> 2264640
#define O_XF     2264640                // emb-gather A-frags -> 131072 -> 2395712 (dead after gx launch)
#define O_WVC    2264640                // gathered Wv columns [1024][512] fp32 (filler-written during LSTM)
#define O_WXFW   2395712                // Wx_fw B-frags -> 262144 -> 2657856 (dead after gx launch)
#define O_WXBW   2657856                // Wx_bw B-frags -> 262144 -> 2920000 (dead after gx launch)
#define O_WPEF   2920000                // Wproj_e B-frags -> 262144 -> 3182144 (filler-written during LSTM)
#define O_NNWF   3313216                // nnW B-frags -> 65536 -> 3378752 (mega_prep-written, read by gxw)
#define O_GX     3378752                // [2][1024][2048] fp32 -> 7573056 (LSTM-live)

typedef __attribute__((ext_vector_type(8))) short short8;
typedef __attribute__((ext_vector_type(4))) float f32x4;

__device__ __forceinline__ float sigf(float x) { return 1.0f / (1.0f + expf(-x)); }
__device__ __forceinline__ unsigned short tobf(float x) {
    __hip_bfloat16 h = __float2bfloat16(x);
    return *reinterpret_cast<unsigned short*>(&h);
}

// ---------------- device conversion bodies ----------------
__device__ __forceinline__ void dconvA(const float* __restrict__ A, uint4* __restrict__ out,
                                       int K, const int* __restrict__ gidx, int g) {
    int Kd = K >> 5;
    int lane = g & 63, t = g >> 6;
    int ks = t % Kd, mt = t / Kd;
    int m = mt * 16 + (lane & 15);
    int k0 = ks * 32 + (lane >> 4) * 8;
    const float* p = (gidx ? A + (size_t)gidx[m] * K : A + (size_t)m * K) + k0;
    float4 f0 = *(const float4*)(p);
    float4 f1 = *(const float4*)(p + 4);
    unsigned short u[8] = {tobf(f0.x), tobf(f0.y), tobf(f0.z), tobf(f0.w),
                           tobf(f1.x), tobf(f1.y), tobf(f1.z), tobf(f1.w)};
    out[g] = *(uint4*)u;
}

__device__ __forceinline__ void dconvB(const float* __restrict__ B, uint4* __restrict__ out,
                                       int N, int K, int g) {
    int Kd = K >> 5;
    int lane = g & 63, t = g >> 6;
    int ks = t % Kd, nt = t / Kd;
    int n = nt * 16 + (lane & 15);
    int k0 = ks * 32 + (lane >> 4) * 8;
    const float* p = B + (size_t)k0 * N + n;
    unsigned short u[8];
#pragma unroll
    for (int j = 0; j < 8; j++) u[j] = tobf(p[(size_t)j * N]);
    out[g] = *(uint4*)u;
}

// ---------------- fused prolog: zero + all pre-LSTM converts ----------------
__global__ __launch_bounds__(256) void mega_prep_k(float4* __restrict__ zdst, int zn4,
                                                   const float* __restrict__ emb,
                                                   const int* __restrict__ targets,
                                                   uint4* __restrict__ xf,
                                                   const float* __restrict__ wxfw, uint4* __restrict__ wxfwf,
                                                   const float* __restrict__ wxbw, uint4* __restrict__ wxbwf,
                                                   const float* __restrict__ wpt, uint4* __restrict__ wptaf,
                                                   const float* __restrict__ nnw, uint4* __restrict__ nnwf) {
    int blk = blockIdx.x, tid = threadIdx.x;
    if (blk < 548) {
        int i = blk * 256 + tid;
        if (i < zn4) zdst[i] = make_float4(0.f, 0.f, 0.f, 0.f);
    } else if (blk < 676) {
        dconvA(emb, xf, 256, targets, (blk - 548) * 256 + tid);
    } else if (blk < 932) {
        dconvB(wxfw, wxfwf, 2048, 256, (blk - 676) * 256 + tid);
    } else if (blk < 1188) {
        dconvB(wxbw, wxbwf, 2048, 256, (blk - 932) * 256 + tid);
    } else if (blk < 1316) {
        dconvA(wpt, wptaf, 256, nullptr, (blk - 1188) * 256 + tid);   // Wproj_t A-frags [1024][256]
    } else {
        dconvB(nnw, nnwf, 512, 256, (blk - 1316) * 256 + tid);        // nnW B-frags [256][512]
    }
}

// ---------------- generic MFMA GEMM body: C = act(A@B + bias), fp32 out ----------------
template <int ACT>
__device__ __forceinline__ void gemm_body(const uint4* __restrict__ af,
                                          const uint4* __restrict__ bf,
                                          const float* __restrict__ bias,
                                          float* __restrict__ C, int N, int Kd,
                                          int bx, int by) {
    int tid = threadIdx.x, w = tid >> 6, lane = tid & 63;
    int ntb = bx * 8 + w * 2;
    int mtb = by * 8;
    f32x4 acc[8][2];
#pragma unroll
    for (int i = 0; i < 8; i++)
#pragma unroll
        for (int j = 0; j < 2; j++) acc[i][j] = 0.0f;
    for (int ks = 0; ks < Kd; ++ks) {
        uint4 b0 = bf[(size_t)(ntb * Kd + ks) * 64 + lane];
        uint4 b1 = bf[(size_t)((ntb + 1) * Kd + ks) * 64 + lane];
#pragma unroll
        for (int i = 0; i < 8; i++) {
            uint4 a = af[(size_t)((mtb + i) * Kd + ks) * 64 + lane];
            acc[i][0] = __builtin_amdgcn_mfma_f32_16x16x32_bf16(
                *reinterpret_cast<short8*>(&a), *reinterpret_cast<short8*>(&b0), acc[i][0], 0, 0, 0);
            acc[i][1] = __builtin_amdgcn_mfma_f32_16x16x32_bf16(
                *reinterpret_cast<short8*>(&a), *reinterpret_cast<short8*>(&b1), acc[i][1], 0, 0, 0);
        }
    }
    int n0 = ntb * 16 + (lane & 15);
    int q = lane >> 4;
    float bs0 = bias ? bias[n0] : 0.f;
    float bs1 = bias ? bias[n0 + 16] : 0.f;
#pragma unroll
    for (int i = 0; i < 8; i++)
#pragma unroll
        for (int r = 0; r < 4; r++) {
            int m = (mtb + i) * 16 + q * 4 + r;
            float v0 = acc[i][0][r] + bs0;
            float v1 = acc[i][1][r] + bs1;
            if (ACT == 1) { v0 = tanhf(v0); v1 = tanhf(v1); }
            C[(size_t)m * N + n0] = v0;
            C[(size_t)m * N + n0 + 16] = v1;
        }
}

// merged: both gx GEMMs + W_comb GEMM
__global__ __launch_bounds__(256) void gxw_gemm_k(const uint4* __restrict__ xf,
                                                  const uint4* __restrict__ wxfwf,
                                                  const uint4* __restrict__ wxbwf,
                                                  const float* __restrict__ b_fw,
                                                  const float* __restrict__ b_bw,
                                                  float* __restrict__ gx,
                                                  const uint4* __restrict__ wptaf,
                                                  const uint4* __restrict__ nnwf,
                                                  float* __restrict__ wcomb) {
    int bx = blockIdx.x;
    if (bx < 16)      gemm_body<0>(xf, wxfwf, b_fw, gx, 2048, 8, bx, blockIdx.y);
    else if (bx < 32) gemm_body<0>(xf, wxbwf, b_bw, gx + 2097152, 2048, 8, bx - 16, blockIdx.y);
    else              gemm_body<0>(wptaf, nnwf, nullptr, wcomb, 512, 8, bx - 32, blockIdx.y);
}

// merged: ts = hcat@Wproj_e (plain) and tt = tanh(hcat@W_comb + nnb)
__global__ __launch_bounds__(256) void projts_k(const uint4* __restrict__ hcatf,
                                                const uint4* __restrict__ wpef,
                                                const uint4* __restrict__ wcombf,
                                                const float* __restrict__ nnb,
                                                float* __restrict__ ts,
                                                float* __restrict__ tt) {
    int bx = blockIdx.x;
    if (bx < 4) gemm_body<0>(hcatf, wpef, nullptr, ts, 512, 32, bx, blockIdx.y);
    else        gemm_body<1>(hcatf, wcombf, nnb, tt, 512, 32, bx - 4, blockIdx.y);
}

// ---------------- fused persistent LSTM + LSTM-independent fillers (NO spinners) ----------------
// blocks   0..31 : r1's proven barrier-protocol LSTM (verbatim).
// blocks  32..156: null state + null denominator.
// blocks 157..284: gather emission's Wv columns into O_WVC.
// blocks 285..540: Wproj_e -> B-frags (O_WPEF).
// blocks 541..796: W_comb -> B-frags (O_WCOMBF).
// r11/r13 verdict: both FMA and fabric-streaming spinners SLOW the LSTM (446->470);
// no clock domain is throttled — the 7 us/step is genuine chained fabric latency.
__global__ __launch_bounds__(256, 1) void lstm_fused_k(const float* __restrict__ wh_fw,
                                                       const float* __restrict__ wh_bw,
                                                       const float* __restrict__ gx,
                                                       const int* __restrict__ lengths,
                                                       unsigned* __restrict__ hbuf32,
                                                       unsigned* __restrict__ hcat32,
                                                       unsigned* __restrict__ slots,
                                                       const float* __restrict__ Wv,
                                                       const float* __restrict__ emb,
                                                       const int* __restrict__ tnull,
                                                       const float* __restrict__ nnW,
                                                       const float* __restrict__ nnb,
                                                       const float* __restrict__ bv,
                                                       float* __restrict__ ns,
                                                       float* __restrict__ nd,
                                                       const int* __restrict__ sources,
                                                       float* __restrict__ wvc,
                                                       const float* __restrict__ wpe, uint4* __restrict__ wpef,
                                                       const float* __restrict__ wcomb, uint4* __restrict__ wcombf) {
    int blk = blockIdx.x;
    int tid = threadIdx.x;

    if (blk >= 541) {                 // W_comb -> B-frags (N=512, K=1024)
        dconvB(wcomb, wcombf, 512, 1024, (blk - 541) * 256 + tid);
        return;
    }
    if (blk >= 285) {                 // Wproj_e B-frags
        dconvB(wpe, wpef, 512, 1024, (blk - 285) * 256 + tid);
        return;
    }
    if (blk >= 157) {
        // ---- gather emission's Wv columns: wvc[ci][k] = Wv[k][sources[ci]] ----
        int cb = blk - 157;           // 0..127, 8 columns each
#pragma unroll
        for (int cc = 0; cc < 8; ++cc) {
            int ci = cb * 8 + cc;
            int c = sources[ci];
            float v0 = Wv[(size_t)tid * VS + c];
            float v1 = Wv[(size_t)(tid + 256) * VS + c];
            wvc[(size_t)ci * 512 + tid] = v0;
            wvc[(size_t)ci * 512 + 256 + tid] = v1;
        }
        return;
    }
    if (blk >= 32) {
        // ---- null state + denom ----
        __shared__ float xn[En];
        __shared__ float nsl[Hn];
        __shared__ float red[4];
        int bid = blk - 32;
        xn[tid] = emb[(size_t)tnull[0] * En + tid];
        __syncthreads();
#pragma unroll
        for (int hh = 0; hh < 2; hh++) {
            int h = tid + hh * 256;
            float a = nnb[h];
            for (int e = 0; e < En; e++) a += xn[e] * nnW[(size_t)e * Hn + h];
            float v = tanhf(a);
            nsl[h] = v;
            if (bid == 0) ns[h] = v;
        }
        __syncthreads();
        int v = bid * 256 + tid;
        float a = bv[v];
        for (int k = 0; k < Hn; k++) a += nsl[k] * Wv[(size_t)k * VS + v];
        float e = expf(a);
        for (int o = 1; o < 64; o <<= 1) e += __shfl_xor(e, o);
        if ((tid & 63) == 0) red[tid >> 6] = e;
        __syncthreads();
        if (tid == 0) atomicAdd(nd, red[0] + red[1] + red[2] + red[3]);
        return;
    }

    // ---- r1 persistent bidirectional LSTM (verbatim) ----
    __shared__ uint4 whf[8192];       // 128 KB B-frags
    __shared__ float raw[32][129];
    __shared__ int lenS[16];
    int dir = blk >> 4;
    int u0 = (blk & 15) * 32;
    const float* wh = dir ? wh_bw : wh_fw;
    if (tid < 16) lenS[tid] = lengths[tid];

    // one-time Wh -> bf16 B-frag staging
    for (int chunk = 0; chunk < 16; ++chunk) {
#pragma unroll
        for (int it = 0; it < 16; ++it) {
            int li = it * 256 + tid;
            int kl = li >> 7, c = li & 127;
            int g = c >> 5, ub = c & 31;
            raw[kl][c] = wh[(size_t)(chunk * 32 + kl) * 2048 + g * 512 + u0 + ub];
        }
        __syncthreads();
#pragma unroll
        for (int it = 0; it < 2; ++it) {
            int idx = tid * 2 + it;
            int w = idx >> 7, t = (idx >> 6) & 1, lane = idx & 63;
            int n = lane & 15, uu = n >> 1, p = n & 1;
            int cc = (t * 2 + p) * 32 + w * 8 + uu;
            int kb = (lane >> 4) * 8;
            unsigned short u8[8];
#pragma unroll
            for (int j = 0; j < 8; j++) u8[j] = tobf(raw[kb + j][cc]);
            whf[((w * 2 + t) * 16 + chunk) * 64 + lane] = *(uint4*)u8;
        }
        __syncthreads();
    }

    int wv = tid >> 6, lane = tid & 63;
    int n = lane & 15, uu = n >> 1, q = lane >> 4;
    int u = u0 + wv * 8 + uu;
    float creg[4] = {0.f, 0.f, 0.f, 0.f};
    unsigned short hbf[4] = {0, 0, 0, 0};

    for (int s = 0; s < 64; ++s) {
        // ---- gx prefetch (normal cached loads, issued first) ----
        float gxi[4], gxj[4], gxf[4], gxo[4];
#pragma unroll
        for (int r = 0; r < 4; r++) {
            int b = q * 4 + r;
            int len = lenS[b];
            int tc = dir ? (len - 1 - s) : s;
            tc = tc < 0 ? 0 : tc;
            const float* gp = gx + (size_t)dir * 2097152 + (size_t)(b * 64 + tc) * 2048 + u;
            gxi[r] = gp[0]; gxj[r] = gp[512]; gxf[r] = gp[1024]; gxo[r] = gp[1536];
        }
        // ---- A-frags: bypass-atomic u64 loads of h (b = n, k = units) ----
        const unsigned long long* hb64 =
            (const unsigned long long*)(hbuf32 + (((s & 1) * 2 + dir) * 16) * 256);
        unsigned long long h64[32];
#pragma unroll
        for (int ks = 0; ks < 16; ks++) {
            int idx = n * 128 + ks * 8 + q * 2;
            h64[2 * ks] = __hip_atomic_load(hb64 + idx, __ATOMIC_RELAXED, __HIP_MEMORY_SCOPE_AGENT);
            h64[2 * ks + 1] = __hip_atomic_load(hb64 + idx + 1, __ATOMIC_RELAXED, __HIP_MEMORY_SCOPE_AGENT);
        }
        // ---- MFMA ----
        f32x4 acc0 = {0.f, 0.f, 0.f, 0.f}, acc1 = {0.f, 0.f, 0.f, 0.f};
#pragma unroll
        for (int ks = 0; ks < 16; ks++) {
            unsigned long long av[2] = {h64[2 * ks], h64[2 * ks + 1]};
            short8 a = *reinterpret_cast<short8*>(av);
            uint4 b0 = whf[((wv * 2 + 0) * 16 + ks) * 64 + lane];
            uint4 b1 = whf[((wv * 2 + 1) * 16 + ks) * 64 + lane];
            acc0 = __builtin_amdgcn_mfma_f32_16x16x32_bf16(a, *reinterpret_cast<short8*>(&b0), acc0, 0, 0, 0);
            acc1 = __builtin_amdgcn_mfma_f32_16x16x32_bf16(a, *reinterpret_cast<short8*>(&b1), acc1, 0, 0, 0);
        }
        // ---- gates (even lanes i/f in acc0/acc1; odd lanes j/o of same unit) ----
#pragma unroll
        for (int r = 0; r < 4; r++) {
            float jvv = __shfl_xor(acc0[r], 1);
            float ovv = __shfl_xor(acc1[r], 1);
            int b = q * 4 + r;
            int len = lenS[b];
            float gi = acc0[r] + gxi[r];
            float gj = jvv + gxj[r];
            float gf = acc1[r] + gxf[r];
            float go = ovv + gxo[r];
            float cn = sigf(gf + 1.0f) * creg[r] + sigf(gi) * tanhf(gj);
            float hn = sigf(go) * tanhf(cn);
            if (s < len) { creg[r] = cn; hbf[r] = tobf(hn); }
        }
        // ---- pack unit pairs and store (lanes n%4==0 own units u,u+1) ----
#pragma unroll
        for (int r = 0; r < 4; r++) {
            unsigned self = hbf[r];
            unsigned part = (unsigned)__shfl_xor((int)self, 2) & 0xffffu;
            if ((n & 3) == 0) {
                unsigned pk = self | (part << 16);
                int b = q * 4 + r;
                __hip_atomic_store(
                    hbuf32 + ((((s + 1) & 1) * 2 + dir) * 16 + b) * 256 + (u >> 1), pk,
                    __ATOMIC_RELAXED, __HIP_MEMORY_SCOPE_AGENT);
                int len = lenS[b];
                if (s < len) {
                    int tin = dir ? (len - 1 - s) : s;
                    int row = b * 64 + tin, col = dir * 512 + u;
                    int mt = row >> 4, ksx = col >> 5;
                    int lanep = (row & 15) | (((col >> 3) & 3) << 4);
                    hcat32[(size_t)(((mt * 32 + ksx) * 64 + lanep) * 4) + ((col & 7) >> 1)] = pk;
                }
            }
        }
        if (s == 63) break;
        __syncthreads();  // vmcnt(0) drain: h stores at coherence point before flag
        if (tid == 0)     // RELAXED flag: no per-step buffer_wbl2
            __hip_atomic_store(&slots[blk * 64], (unsigned)(s + 1), __ATOMIC_RELAXED,
                               __HIP_MEMORY_SCOPE_AGENT);
        if (tid < 16) {
            while (__hip_atomic_load(&slots[(dir * 16 + tid) * 64], __ATOMIC_RELAXED,
                                     __HIP_MEMORY_SCOPE_AGENT) < (unsigned)(s + 1)) {
                __builtin_amdgcn_s_sleep(1);
            }
        }
        __syncthreads();
    }
}

// ---------------- convA (ts->tsf, blocks 0..255) + transition (blocks 256..1279) ----------------
__global__ __launch_bounds__(256) void convtr_k(const float* __restrict__ ts,
                                                uint4* __restrict__ tsf,
                                                const float* __restrict__ tt,
                                                const float* __restrict__ Wj,
                                                const float* __restrict__ bj,
                                                const float* __restrict__ Wp0,
                                                const float* __restrict__ bp0,
                                                float* __restrict__ trans,
                                                float* __restrict__ tlog) {
    __shared__ float ttl[512];
    __shared__ float jrow[Jn], ljrow[Jn];
    __shared__ float sred[256];
    __shared__ float p0_s, lp0_s;
    int blk = blockIdx.x;
    int tid = threadIdx.x;
    if (blk < 256) {
        dconvA(ts, tsf, 512, nullptr, blk * 256 + tid);
        return;
    }
    int tb = blk - 256;
    int b = tb >> 6, i = tb & 63;
    {
        const float* trr = tt + (size_t)tb * 512;
        if (tid < 128) *(float4*)&ttl[tid * 4] = *(const float4*)(trr + tid * 4);
    }
    __syncthreads();
    bool isj = tid < Jn;
    bool isp = tid == Jn;
    float l = 0.f;
    if (isj || isp) {
        const float* wb = isj ? (Wj + tid) : Wp0;
        int stride = isj ? Jn : 1;
        float a = isj ? bj[tid] : bp0[0];
        for (int k = 0; k < 512; k++) a += ttl[k] * wb[(size_t)k * stride];
        l = a;
    }
    sred[tid] = isj ? l : -1e30f;
    __syncthreads();
    for (int o = 128; o > 0; o >>= 1) {
        if (tid < o) sred[tid] = fmaxf(sred[tid], sred[tid + o]);
        __syncthreads();
    }
    float m = sred[0];
    __syncthreads();
    float ex = isj ? expf(l - m) : 0.f;
    sred[tid] = ex;
    __syncthreads();
    for (int o = 128; o > 0; o >>= 1) {
        if (tid < o) sred[tid] += sred[tid + o];
        __syncthreads();
    }
    float S = sred[0];
    if (isj) {
        jrow[tid] = ex / S;
        ljrow[tid] = (l - m) - logf(S);
    }
    if (isp) {
        float pv = 1.f / (1.f + expf(-l));
        p0_s = pv;
        lp0_s = logf(pv);
    }
    __syncthreads();
    if (tid < 128) {
        int j = tid;
        float tv, lv;
        if (j < 64) {
            int id = Mn + j - i;
            tv = jrow[id];
            lv = ljrow[id];
        } else {
            bool dg = (j - 64) == i;
            tv = dg ? p0_s : 0.f;
            lv = dg ? lp0_s : 0.f;
        }
        size_t r1 = (size_t)(b * 128 + i) * 128 + j;
        size_t r2 = (size_t)(b * 128 + 64 + i) * 128 + j;
        trans[r1] = tv;
        trans[r2] = tv;
        tlog[r1] = lv;
        tlog[r2] = lv;
    }
}

// ---------------- Phase A: MFMA row-sum-of-exp, 512 threads (8 waves, 1 nt/wave) ----------------
// r14 fix: was 256 threads + 128 KB LDS -> 1 block/CU -> only 1 wave/SIMD; every L2
// A-frag latency exposed. Now 8 waves/CU hide it; each wave owns ONE 16-col N-tile.
__global__ __launch_bounds__(512) void phaseA_mfma_k(const uint4* __restrict__ tsb,
                                                     const float* __restrict__ Wv,
                                                     const float* __restrict__ bv,
                                                     float* __restrict__ denom) {
    __shared__ uint4 wls[8192];      // 128 KB: [8 tiles][16 ks][64 lane]
    __shared__ float redL[8][128];
    int tid = threadIdx.x;
    int wave = tid >> 6, lane = tid & 63;
    // ---- cooperative Wv -> bf16 B-frag conversion into LDS (16 iters @ 512 thr) ----
    for (int it = 0; it < 16; ++it) {
        int g = it * 512 + tid;          // uint4 index in [0, 8192)
        int gl = g & 63, t = g >> 6;     // t in [0,128): tile*16 + ks
        int ks = t & 15, tl = t >> 4;
        int nt = blockIdx.x * 8 + tl;
        int nn = nt * 16 + (gl & 15);
        int k0 = ks * 32 + (gl >> 4) * 8;
        const float* p = Wv + (size_t)k0 * VS + nn;
        unsigned short u[8];
#pragma unroll
        for (int j = 0; j < 8; j++) u[j] = tobf(p[(size_t)j * VS]);
        wls[g] = *(uint4*)u;
    }
    __syncthreads();

    int ntb = blockIdx.x * 8 + wave;     // one N-tile per wave
    float bv0 = bv[ntb * 16 + (lane & 15)];
    int q = lane >> 4;
    for (int mc = 0; mc < 8; ++mc) {
        f32x4 acc[8];
#pragma unroll
        for (int i = 0; i < 8; i++) acc[i] = 0.0f;
#pragma unroll 4
        for (int ks = 0; ks < 16; ++ks) {
            uint4 bt = wls[(wave * 16 + ks) * 64 + lane];
            short8 b = *reinterpret_cast<short8*>(&bt);
#pragma unroll
            for (int i = 0; i < 8; i++) {
                int mt = mc * 8 + i;
                uint4 t = tsb[(size_t)(mt * 16 + ks) * 64 + lane];
                acc[i] = __builtin_amdgcn_mfma_f32_16x16x32_bf16(
                    *reinterpret_cast<short8*>(&t), b, acc[i], 0, 0, 0);
            }
        }
#pragma unroll
        for (int i = 0; i < 8; i++) {
#pragma unroll
            for (int r = 0; r < 4; r++) {
                float e = __expf(acc[i][r] + bv0);
                e += __shfl_xor(e, 1);
                e += __shfl_xor(e, 2);
                e += __shfl_xor(e, 4);
                e += __shfl_xor(e, 8);
                if ((lane & 15) == 0) redL[wave][i * 16 + q * 4 + r] = e;
            }
        }
        __syncthreads();
        if (tid < 128) {
            float v = redL[0][tid] + redL[1][tid] + redL[2][tid] + redL[3][tid] +
                      redL[4][tid] + redL[5][tid] + redL[6][tid] + redL[7][tid];
            atomicAdd(&denom[mc * 128 + tid], v);
        }
        __syncthreads();
    }
}

// ---------------- emission assembly (reads pre-gathered Wv columns) ----------------
__global__ __launch_bounds__(512) void emission_k(const float* __restrict__ ts,
                                                  const float* __restrict__ wvc,
                                                  const float* __restrict__ bv,
                                                  const int* __restrict__ sources,
                                                  const float* __restrict__ ns,
                                                  const float* __restrict__ denom,
                                                  const float* __restrict__ nulld,
                                                  float* __restrict__ em) {
    __shared__ float colv[512];
    __shared__ float red[64][9];
    __shared__ float red2[8];
    __shared__ float env_s, bvc_s;
    int b = blockIdx.y, sc = blockIdx.x;
    int tid = threadIdx.x;
    for (int qq = 0; qq < 8; ++qq) {
        int s = sc * 8 + qq;
        int ci = b * 64 + s;
        __syncthreads();
        colv[tid] = wvc[(size_t)ci * 512 + tid];
        if (tid == 0) bvc_s = bv[sources[ci]];
        __syncthreads();
        int r = tid & 63, ksl = tid >> 6;
        const float* tr = ts + (size_t)(b * 64 + r) * 512 + ksl * 64;
        float p = 0.f;
#pragma unroll
        for (int k4 = 0; k4 < 16; k4++) {
            float4 t4 = *(const float4*)(tr + k4 * 4);
            float4 c4 = *(const float4*)&colv[ksl * 64 + k4 * 4];
            p += t4.x * c4.x + t4.y * c4.y + t4.z * c4.z + t4.w * c4.w;
        }
        red[r][ksl] = p;
        if (tid < 8) {
            float pn = 0.f;
#pragma unroll
            for (int k4 = 0; k4 < 16; k4++) {
                float4 n4 = *(const float4*)(ns + tid * 64 + k4 * 4);
                float4 c4 = *(const float4*)&colv[tid * 64 + k4 * 4];
                pn += n4.x * c4.x + n4.y * c4.y + n4.z * c4.z + n4.w * c4.w;
            }
            red2[tid] = pn;
        }
        __syncthreads();
        if (tid < 64) {
            float dot = red[tid][0] + red[tid][1] + red[tid][2] + red[tid][3] +
                        red[tid][4] + red[tid][5] + red[tid][6] + red[tid][7];
            float ew = expf(dot + bvc_s) / denom[b * 64 + tid];
            em[(size_t)(b * 128 + tid) * 64 + s] = ew;
        } else if (tid == 64) {
            float dn = red2[0] + red2[1] + red2[2] + red2[3] +
                       red2[4] + red2[5] + red2[6] + red2[7];
            env_s = expf(dn + bvc_s) / nulld[0];
        }
        __syncthreads();
        if (tid < 64) em[(size_t)(b * 128 + 64 + tid) * 64 + s] = env_s;
    }
}

extern "C" void kernel_launch(void* const* d_in, const int* in_sizes, int n_in,
                              void* d_out, int out_size, void* d_ws, size_t ws_size,
                              hipStream_t stream) {
    const int* sources = (const int*)d_in[0];
    const int* targets = (const int*)d_in[1];
    const int* tnull = (const int*)d_in[2];
    const int* lengths = (const int*)d_in[3];
    const float* emb = (const float*)d_in[4];
    const float* nnW = (const float*)d_in[5];
    const float* nnb = (const float*)d_in[6];
    const float* Wx_fw = (const float*)d_in[7];
    const float* Wh_fw = (const float*)d_in[8];
    const float* b_fw = (const float*)d_in[9];
    const float* Wx_bw = (const float*)d_in[10];
    const float* Wh_bw = (const float*)d_in[11];
    const float* b_bw = (const float*)d_in[12];
    const float* Wproj_e = (const float*)d_in[13];
    const float* Wv = (const float*)d_in[14];
    const float* bv = (const float*)d_in[15];
    const float* Wproj_t = (const float*)d_in[16];
    const float* Wj = (const float*)d_in[17];
    const float* bj = (const float*)d_in[18];
    const float* Wp0 = (const float*)d_in[19];
    const float* bp0 = (const float*)d_in[20];

    float* ws = (float*)d_ws;
    float* out = (float*)d_out;
    float* out_em = out;                     // [16][128][64]
    float* out_tr = out + 131072;            // [16][128][128]
    float* out_tl = out + 131072 + 262144;   // [16][128][128]

    // 1) fused zero + all pre-LSTM converts (XF, WXFW, WXBW, Wproj_t A-frags, nnW B-frags)
    mega_prep_k<<<1380, 256, 0, stream>>>((float4*)ws, ZERO_N / 4,
                                          emb, targets, (uint4*)(ws + O_XF),
                                          Wx_fw, (uint4*)(ws + O_WXFW),
                                          Wx_bw, (uint4*)(ws + O_WXBW),
                                          Wproj_t, (uint4*)(ws + O_WPTAF),
                                          nnW, (uint4*)(ws + O_NNWF));

    // 2) gx (both dirs) + W_comb = Wproj_t @ nnW (one launch)
    gxw_gemm_k<<<dim3(36, 8), 256, 0, stream>>>((uint4*)(ws + O_XF), (uint4*)(ws + O_WXFW),
                                                (uint4*)(ws + O_WXBW), b_fw, b_bw, ws + O_GX,
                                                (uint4*)(ws + O_WPTAF), (uint4*)(ws + O_NNWF),
                                                ws + O_WCOMB);

    // 3) persistent LSTM + fillers (no spinners — they measurably hurt)
    lstm_fused_k<<<797, 256, 0, stream>>>(Wh_fw, Wh_bw, ws + O_GX, lengths,
                                          (unsigned*)(ws + O_HBUF), (unsigned*)(ws + O_HCATF),
                                          (unsigned*)(ws + O_SLOTS),
                                          Wv, emb, tnull, nnW, nnb, bv,
                                          ws + O_NS, ws + O_NULLD,
                                          sources, ws + O_WVC,
                                          Wproj_e, (uint4*)(ws + O_WPEF),
                                          ws + O_WCOMB, (uint4*)(ws + O_WCOMBF));

    // 4) projections: ts (plain) + tt (tanh, via W_comb associativity) — one launch
    projts_k<<<dim3(8, 8), 256, 0, stream>>>((uint4*)(ws + O_HCATF), (uint4*)(ws + O_WPEF),
                                             (uint4*)(ws + O_WCOMBF), nnb,
                                             ws + O_TS, ws + O_TT);

    // 5) ts -> bf16 A-frags + transition (both small-LDS, both depend only on projts)
    convtr_k<<<1280, 256, 0, stream>>>(ws + O_TS, (uint4*)(ws + O_TSF),
                                       ws + O_TT, Wj, bj, Wp0, bp0, out_tr, out_tl);

    // 6) phaseA (denominators), 512-thread / 8-wave occupancy version
    phaseA_mfma_k<<<250, 512, 0, stream>>>((const uint4*)(ws + O_TSF), Wv, bv, ws + O_DENOM);

    // 7) emission output (coalesced reads of pre-gathered Wv columns)
    emission_k<<<dim3(8, 16), 512, 0, stream>>>(ws + O_TS, ws + O_WVC, bv, sources, ws + O_NS,
                                                ws + O_DENOM, ws + O_NULLD, out_em);
}